// Round 10
// baseline (217.807 us; speedup 1.0000x reference)
//
#include <hip/hip_runtime.h>

#define PPB   128
#define NZ    8
#define INC   64
#define OUTC  128
#define NB    4
#define HH    256
#define WWD   256
#define HWD   (HH * WWD)
#define NSEG  (NB * HH)          // 1024 row segments (b*HH + h)
#define NCELL (NB * HH * WWD)    // 262144 cells (flat bev index)

typedef __attribute__((ext_vector_type(8))) short bf16x8;
typedef __attribute__((ext_vector_type(4))) float f32x4;

__device__ __forceinline__ unsigned bf16_rne(float x) {
    unsigned u = __float_as_uint(x);
    return (u + 0x7FFFu + ((u >> 16) & 1u)) >> 16;
}
__device__ __forceinline__ unsigned pack2(float lo, float hi) {   // dword d = (ch 2d, ch 2d+1)
    return bf16_rne(lo) | (bf16_rne(hi) << 16);
}

// ---------------- pass 1: z histogram + cell histogram ----------------
__global__ void hist_kernel(const int* __restrict__ z_idx, const int* __restrict__ batch_idx,
                            const int* __restrict__ d0_idx, const int* __restrict__ d1_idx,
                            int* __restrict__ counts, int* __restrict__ cellhist, int n) {
    __shared__ int lc[NZ];
    int t = threadIdx.x;
    if (t < NZ) lc[t] = 0;
    __syncthreads();
    int i = blockIdx.x * blockDim.x + t;
    if (i < n) {
        int z = z_idx[i]; z = z < 0 ? 0 : (z > NZ - 1 ? NZ - 1 : z);
        atomicAdd(&lc[z], 1);
        int cell = (batch_idx[i] * HH + d0_idx[i]) * WWD + d1_idx[i];
        atomicAdd(&cellhist[cell], 1);
    }
    __syncthreads();
    if (t < NZ && lc[t] > 0) atomicAdd(&counts[t], lc[t]);
}

// ---------------- pass 2a: z padded prefix ----------------
__global__ void prefix_z_kernel(const int* __restrict__ counts, int* __restrict__ pstart) {
    if (threadIdx.x == 0 && blockIdx.x == 0) {
        int off = 0;
        for (int z = 0; z < NZ; ++z) {
            pstart[z] = off;
            off += ((counts[z] + PPB - 1) / PPB) * PPB;
        }
        pstart[NZ] = off;
    }
}

// ---------------- pass 2b: 3-kernel exclusive scan over 262144 cell counts ----------------
__global__ __launch_bounds__(256) void scan_local(const int* __restrict__ cellhist,
                                                  int* __restrict__ cellstart,
                                                  int* __restrict__ chunksum) {
    __shared__ int ts[256];
    int t = threadIdx.x;
    int base = blockIdx.x * 1024 + t * 4;
    int4 v = *(const int4*)&cellhist[base];
    int s = v.x + v.y + v.z + v.w;
    ts[t] = s;
    __syncthreads();
    for (int d = 1; d < 256; d <<= 1) {
        int x = (t >= d) ? ts[t - d] : 0;
        __syncthreads();
        ts[t] += x;
        __syncthreads();
    }
    int excl = ts[t] - s;
    int4 o;
    o.x = excl; o.y = excl + v.x; o.z = o.y + v.y; o.w = o.z + v.z;
    *(int4*)&cellstart[base] = o;
    if (t == 255) chunksum[blockIdx.x] = ts[255];
}

__global__ __launch_bounds__(256) void scan_top(int* __restrict__ chunksum,
                                                int* __restrict__ cellstart) {
    __shared__ int ts[256];
    int t = threadIdx.x;
    int s = chunksum[t];
    ts[t] = s;
    __syncthreads();
    for (int d = 1; d < 256; d <<= 1) {
        int x = (t >= d) ? ts[t - d] : 0;
        __syncthreads();
        ts[t] += x;
        __syncthreads();
    }
    chunksum[t] = ts[t] - s;
    if (t == 255) cellstart[NCELL] = ts[255];
}

__global__ __launch_bounds__(256) void scan_add(int* __restrict__ cellstart,
                                                const int* __restrict__ chunksum) {
    int off = chunksum[blockIdx.x];
    if (off == 0) return;
    int base = blockIdx.x * 1024 + threadIdx.x * 4;
    int4 v = *(int4*)&cellstart[base];
    v.x += off; v.y += off; v.z += off; v.w += off;
    *(int4*)&cellstart[base] = v;
}

// ---------------- pass 3: scatter ids into z bins + cell-sorted positions ----------------
__global__ void scatter_kernel(const int* __restrict__ z_idx, const int* __restrict__ batch_idx,
                               const int* __restrict__ d0_idx, const int* __restrict__ d1_idx,
                               const int* __restrict__ pstart, int* __restrict__ cursors,
                               const int* __restrict__ cellstart, int* __restrict__ cellcur,
                               int* __restrict__ bins, int* __restrict__ segpos, int n) {
    __shared__ int lc[NZ];
    __shared__ int lbase[NZ];
    int t = threadIdx.x;
    if (t < NZ) lc[t] = 0;
    __syncthreads();
    int i = blockIdx.x * blockDim.x + t;
    int z = 0, rank = 0;
    bool valid = (i < n);
    if (valid) {
        z = z_idx[i]; z = z < 0 ? 0 : (z > NZ - 1 ? NZ - 1 : z);
        rank = atomicAdd(&lc[z], 1);
    }
    __syncthreads();
    if (t < NZ) lbase[t] = (lc[t] > 0) ? atomicAdd(&cursors[t], lc[t]) : 0;
    __syncthreads();
    if (valid) {
        int slot = pstart[z] + lbase[z] + rank;
        bins[slot] = i;
        int cell = (batch_idx[i] * HH + d0_idx[i]) * WWD + d1_idx[i];
        int r2 = atomicAdd(&cellcur[cell], 1);
        segpos[slot] = 1 + cellstart[cell] + r2;   // row 0 of bevf = dump for padding
    }
}

// ---------------- pass 4: bf16 MFMA GEMM per z-bin -> bf16 rows at cell-sorted pos ----------------
// LDS: Abf[128 p][64 k] bf16, Wbf[128 c][64 k] bf16, both XOR-swizzled (byte ^= (row&7)<<4).
// 4 waves; wave (wr,wc) computes 64x64 tile via 32x mfma_f32_16x16x32_bf16.
// Epilogue: shfl_xor(1) pairs adjacent channels -> pack2 -> dword stores into bevf.
__global__ __launch_bounds__(256) void gemm_kernel(
        const float* __restrict__ features, const float* __restrict__ kw,
        const float* __restrict__ bias,
        const int* __restrict__ pstart, const int* __restrict__ bins,
        const int* __restrict__ segpos, unsigned* __restrict__ bevf) {
    __shared__ __align__(16) unsigned short Abf[PPB * INC];    // 16 KiB
    __shared__ __align__(16) unsigned short Wbf[OUTC * INC];   // 16 KiB
    __shared__ int psl[PPB];

    int start = blockIdx.x * PPB;
    int total = pstart[NZ];
    if (start >= total) return;
    int z = 0;
#pragma unroll
    for (int zz = 1; zz < NZ; ++zz)
        if (start >= pstart[zz]) z = zz;

    int tid = threadIdx.x;
    if (tid < PPB) psl[tid] = segpos[start + tid];

    {   // stage A: gather feature rows -> bf16 k-contig, swizzled b128 writes
        int r = tid >> 1, half = tid & 1;
        int raw = bins[start + r];
        int nid = raw < 0 ? 0 : raw;
        const float4* fp = (const float4*)(features + (size_t)nid * INC) + half * 8;
        float4 f[8];
#pragma unroll
        for (int q = 0; q < 8; ++q) f[q] = fp[q];
        unsigned u[16];
#pragma unroll
        for (int m = 0; m < 8; ++m) {
            u[2 * m]     = pack2(f[m].x, f[m].y);
            u[2 * m + 1] = pack2(f[m].z, f[m].w);
        }
        char* base = (char*)Abf;
#pragma unroll
        for (int ch = 0; ch < 4; ++ch) {
            int off = (r * 128 + half * 64 + ch * 16) ^ ((r & 7) << 4);
            uint4 val = make_uint4(u[4 * ch], u[4 * ch + 1], u[4 * ch + 2], u[4 * ch + 3]);
            *(uint4*)(base + off) = val;
        }
    }
    {   // stage W: per-lane column loads (coalesced across lanes, L1/L2-hot) -> bf16
        int c = tid & 127, kh = tid >> 7;
        const float* wp = kw + (size_t)z * INC * OUTC + c;
        float wv[32];
#pragma unroll
        for (int j = 0; j < 32; ++j) wv[j] = wp[(size_t)(kh * 32 + j) * OUTC];
        unsigned u[16];
#pragma unroll
        for (int m = 0; m < 16; ++m) u[m] = pack2(wv[2 * m], wv[2 * m + 1]);
        char* base = (char*)Wbf;
#pragma unroll
        for (int ch = 0; ch < 4; ++ch) {
            int off = (c * 128 + kh * 64 + ch * 16) ^ ((c & 7) << 4);
            uint4 val = make_uint4(u[4 * ch], u[4 * ch + 1], u[4 * ch + 2], u[4 * ch + 3]);
            *(uint4*)(base + off) = val;
        }
    }
    __syncthreads();

    int wv_ = tid >> 6, l = tid & 63;
    int wr = wv_ >> 1, wc = wv_ & 1;

    f32x4 acc[4][4];
#pragma unroll
    for (int i = 0; i < 4; ++i)
#pragma unroll
        for (int j = 0; j < 4; ++j) acc[i][j] = (f32x4){0.f, 0.f, 0.f, 0.f};

#pragma unroll
    for (int kc = 0; kc < 2; ++kc) {
        bf16x8 af[4], bfr[4];
#pragma unroll
        for (int pb = 0; pb < 4; ++pb) {
            int p = wr * 64 + pb * 16 + (l & 15);
            int off = (p * 128 + kc * 64 + (l >> 4) * 16) ^ ((p & 7) << 4);
            af[pb] = *(const bf16x8*)((const char*)Abf + off);
        }
#pragma unroll
        for (int cb = 0; cb < 4; ++cb) {
            int c = wc * 64 + cb * 16 + (l & 15);
            int off = (c * 128 + kc * 64 + (l >> 4) * 16) ^ ((c & 7) << 4);
            bfr[cb] = *(const bf16x8*)((const char*)Wbf + off);
        }
#pragma unroll
        for (int pb = 0; pb < 4; ++pb)
#pragma unroll
            for (int cb = 0; cb < 4; ++cb)
                acc[pb][cb] = __builtin_amdgcn_mfma_f32_16x16x32_bf16(
                    af[pb], bfr[cb], acc[pb][cb], 0, 0, 0);
    }

    float bias_c[4];
#pragma unroll
    for (int cb = 0; cb < 4; ++cb) bias_c[cb] = bias[wc * 64 + cb * 16 + (l & 15)];

    int qb = (l & 1) * 2;
#pragma unroll
    for (int pb = 0; pb < 4; ++pb) {
        int pbase = wr * 64 + pb * 16 + (l >> 4) * 4;
#pragma unroll
        for (int cb = 0; cb < 4; ++cb) {
            float v[4], pv[4];
#pragma unroll
            for (int q = 0; q < 4; ++q) v[q] = acc[pb][cb][q] + bias_c[cb];
#pragma unroll
            for (int q = 0; q < 4; ++q) pv[q] = __shfl_xor(v[q], 1);
            int d = wc * 32 + cb * 8 + ((l & 15) >> 1);
#pragma unroll
            for (int qq = 0; qq < 2; ++qq) {
                int q = qb + qq;
                float lo = (l & 1) ? pv[q] : v[q];
                float hi = (l & 1) ? v[q] : pv[q];
                int pos = psl[pbase + q];
                bevf[(size_t)pos * 64 + d] = pack2(lo, hi);
            }
        }
    }
}

// ---------------- pass 5: register-accumulating per-row reduction (ZERO atomics) ----------------
// Block = row segment (b,h); wave wv owns cells wv*32..wv*32+31 (contiguous bevf ranges);
// lane l = dword l = channels (2l, 2l+1). Cells pre-sorted -> contiguous rows per cell,
// register fp32 accumulate, one plain swizzled LDS write per (cell, dword), then the
// streaming BCHW writeout (1KB contiguous per channel, XCD-contiguous h ranges).
__global__ __launch_bounds__(512) void reduce_kernel(
        const unsigned* __restrict__ bevf, const int* __restrict__ cellstart,
        float* __restrict__ out) {
    __shared__ unsigned tile[256 * 64];   // 64 KiB, [w][dword] rotate-swizzled by w
    int t = threadIdx.x;
    int blk = blockIdx.x;
    blk = (blk & 7) * (NSEG / 8) + (blk >> 3);   // XCD-contiguous segments
    int seg = blk;
    int wv = t >> 6, l = t & 63;

    int cell0 = seg * WWD + wv * 32;
    int cs_n = cellstart[cell0];
    int ce_n = cellstart[cell0 + 1];
    for (int j = 0; j < 32; ++j) {
        int cs = cs_n, ce = ce_n;
        cs_n = ce;
        if (j < 31) ce_n = cellstart[cell0 + j + 2];   // scalar prefetch
        float f0 = 0.f, f1 = 0.f;
        int k = cs;
        for (; k + 1 < ce; k += 2) {                   // 2 loads in flight
            unsigned v0 = bevf[(size_t)(k + 1) * 64 + l];
            unsigned v1 = bevf[(size_t)(k + 2) * 64 + l];
            f0 += __uint_as_float(v0 << 16);
            f1 += __uint_as_float(v0 & 0xFFFF0000u);
            f0 += __uint_as_float(v1 << 16);
            f1 += __uint_as_float(v1 & 0xFFFF0000u);
        }
        if (k < ce) {
            unsigned v0 = bevf[(size_t)(k + 1) * 64 + l];
            f0 += __uint_as_float(v0 << 16);
            f1 += __uint_as_float(v0 & 0xFFFF0000u);
        }
        int w = wv * 32 + j;
        tile[w * 64 + ((l + w) & 63)] = pack2(f0, f1);   // plain write, 2-way max (free)
    }
    __syncthreads();

    int b = seg >> 8, h = seg & 255;
    float* ob = out + (size_t)b * OUTC * HWD + (size_t)h * WWD;
#pragma unroll
    for (int r = 0; r < 16; ++r) {
        int c = wv + 8 * r;        // 0..127
        int d = c >> 1;            // dword index (ch pair 2d,2d+1)
        float* op = ob + (size_t)c * HWD;
#pragma unroll
        for (int q = 0; q < 4; ++q) {
            int w = 64 * q + l;
            unsigned v = tile[w * 64 + ((d + w) & 63)];
            op[w] = __uint_as_float((c & 1) ? (v & 0xFFFF0000u) : (v << 16));
        }
    }
}

// ---------------- fallback (ws too small): direct scattered atomics into BCHW ----------------
__global__ __launch_bounds__(256) void naive_kernel(
        const float* __restrict__ features, const float* __restrict__ kw,
        const float* __restrict__ bias,
        const int* __restrict__ bidx, const int* __restrict__ d0,
        const int* __restrict__ d1, const int* __restrict__ zi,
        float* __restrict__ out, int n) {
    long long gid = (long long)blockIdx.x * blockDim.x + threadIdx.x;
    int pid = (int)(gid >> 7);
    int c   = (int)(gid & (OUTC - 1));
    if (pid >= n) return;
    int z = zi[pid]; z = z < 0 ? 0 : (z > NZ - 1 ? NZ - 1 : z);
    const float4* fp = (const float4*)(features + (size_t)pid * INC);
    const float* wp = kw + (size_t)z * INC * OUTC + c;
    float a0 = bias[c], a1 = 0.f, a2 = 0.f, a3 = 0.f;
#pragma unroll
    for (int i = 0; i < INC / 4; ++i) {
        float4 f = fp[i];
        a0 += f.x * wp[(size_t)(4 * i + 0) * OUTC];
        a1 += f.y * wp[(size_t)(4 * i + 1) * OUTC];
        a2 += f.z * wp[(size_t)(4 * i + 2) * OUTC];
        a3 += f.w * wp[(size_t)(4 * i + 3) * OUTC];
    }
    float acc = (a0 + a1) + (a2 + a3);
    size_t oidx = ((size_t)bidx[pid] * OUTC + c) * HWD + (size_t)d0[pid] * WWD + d1[pid];
    unsafeAtomicAdd(&out[oidx], acc);
}

extern "C" void kernel_launch(void* const* d_in, const int* in_sizes, int n_in,
                              void* d_out, int out_size, void* d_ws, size_t ws_size,
                              hipStream_t stream) {
    const float* features = (const float*)d_in[0];
    const float* kw       = (const float*)d_in[1];
    const float* bias     = (const float*)d_in[2];
    const int* batch_idx  = (const int*)d_in[3];
    const int* d0_idx     = (const int*)d_in[4];
    const int* d1_idx     = (const int*)d_in[5];
    const int* z_idx      = (const int*)d_in[6];
    float* out = (float*)d_out;
    int n = in_sizes[0] / INC;   // number of points

    size_t binsElems = (size_t)n + (size_t)NZ * PPB;
    size_t bevfBytes = (binsElems + 1) * OUTC * 2;           // ~77.5 MB
    size_t metaOff   = (bevfBytes + 255) & ~(size_t)255;
    size_t chOff     = metaOff + 32 * 4;                     // cellhist
    size_t ccOff     = chOff + (size_t)NCELL * 4;            // cellcur
    size_t csOff     = ccOff + (size_t)NCELL * 4;            // cellstart (NCELL+1)
    size_t ckOff     = csOff + (size_t)(NCELL + 4) * 4;      // chunksum (256)
    size_t binsOff   = (ckOff + 256 * 4 + 255) & ~(size_t)255;
    size_t posOff    = binsOff + binsElems * 4;
    size_t need      = posOff + binsElems * 4 + 16;

    if (ws_size >= need) {
        char* ws = (char*)d_ws;
        unsigned* bevf = (unsigned*)ws;
        int* meta      = (int*)(ws + metaOff);   // counts[8], cursors[8], pstart[9]
        int* counts    = meta;
        int* cursors   = meta + 8;
        int* pstart    = meta + 16;
        int* cellhist  = (int*)(ws + chOff);
        int* cellcur   = (int*)(ws + ccOff);
        int* cellstart = (int*)(ws + csOff);
        int* chunksum  = (int*)(ws + ckOff);
        int* bins      = (int*)(ws + binsOff);
        int* segpos    = (int*)(ws + posOff);

        hipMemsetAsync(meta, 0, 32 * 4, stream);
        hipMemsetAsync(cellhist, 0, (size_t)NCELL * 4, stream);
        hipMemsetAsync(cellcur, 0, (size_t)NCELL * 4, stream);
        hipMemsetAsync(bins, 0xFF, binsElems * 4, stream);   // -1 padding
        hipMemsetAsync(segpos, 0, binsElems * 4, stream);    // padding -> dump row 0

        int gb = (n + 255) / 256;
        hist_kernel<<<gb, 256, 0, stream>>>(z_idx, batch_idx, d0_idx, d1_idx,
                                            counts, cellhist, n);
        prefix_z_kernel<<<1, 64, 0, stream>>>(counts, pstart);
        scan_local<<<256, 256, 0, stream>>>(cellhist, cellstart, chunksum);
        scan_top<<<1, 256, 0, stream>>>(chunksum, cellstart);
        scan_add<<<256, 256, 0, stream>>>(cellstart, chunksum);
        scatter_kernel<<<gb, 256, 0, stream>>>(z_idx, batch_idx, d0_idx, d1_idx,
                                               pstart, cursors, cellstart, cellcur,
                                               bins, segpos, n);

        int nblk = (int)((binsElems + PPB - 1) / PPB) + 1;
        gemm_kernel<<<nblk, 256, 0, stream>>>(features, kw, bias, pstart, bins,
                                              segpos, bevf);

        reduce_kernel<<<NSEG, 512, 0, stream>>>(bevf, cellstart, out);
    } else {
        hipMemsetAsync(out, 0, (size_t)out_size * sizeof(float), stream);
        long long threads = (long long)n * OUTC;
        int gb = (int)((threads + 255) / 256);
        naive_kernel<<<gb, 256, 0, stream>>>(features, kw, bias, batch_idx, d0_idx,
                                             d1_idx, z_idx, out, n);
    }
}

// Round 11
// 173.263 us; speedup vs baseline: 1.2571x; 1.2571x over previous
//
#include <hip/hip_runtime.h>

#define PPB   128
#define NZ    8
#define INC   64
#define OUTC  128
#define NB    4
#define HH    256
#define WWD   256
#define HWD   (HH * WWD)
#define NSEG  (NB * HH)          // 1024 row segments (b*HH + h)
#define NCELL (NB * HH * WWD)    // 262144 cells (flat bev index)

typedef __attribute__((ext_vector_type(8))) short bf16x8;
typedef __attribute__((ext_vector_type(4))) float f32x4;

__device__ __forceinline__ unsigned bf16_rne(float x) {
    unsigned u = __float_as_uint(x);
    return (u + 0x7FFFu + ((u >> 16) & 1u)) >> 16;
}
__device__ __forceinline__ unsigned pack2(float lo, float hi) {   // dword d = (ch 2d, ch 2d+1)
    return bf16_rne(lo) | (bf16_rne(hi) << 16);
}

// ---------------- pass 1: z histogram + cell histogram ----------------
__global__ void hist_kernel(const int* __restrict__ z_idx, const int* __restrict__ batch_idx,
                            const int* __restrict__ d0_idx, const int* __restrict__ d1_idx,
                            int* __restrict__ counts, int* __restrict__ cellhist, int n) {
    __shared__ int lc[NZ];
    int t = threadIdx.x;
    if (t < NZ) lc[t] = 0;
    __syncthreads();
    int i = blockIdx.x * blockDim.x + t;
    if (i < n) {
        int z = z_idx[i]; z = z < 0 ? 0 : (z > NZ - 1 ? NZ - 1 : z);
        atomicAdd(&lc[z], 1);
        int cell = (batch_idx[i] * HH + d0_idx[i]) * WWD + d1_idx[i];
        atomicAdd(&cellhist[cell], 1);
    }
    __syncthreads();
    if (t < NZ && lc[t] > 0) atomicAdd(&counts[t], lc[t]);
}

// ---------------- pass 2a: z padded prefix ----------------
__global__ void prefix_z_kernel(const int* __restrict__ counts, int* __restrict__ pstart) {
    if (threadIdx.x == 0 && blockIdx.x == 0) {
        int off = 0;
        for (int z = 0; z < NZ; ++z) {
            pstart[z] = off;
            off += ((counts[z] + PPB - 1) / PPB) * PPB;
        }
        pstart[NZ] = off;
    }
}

// ---------------- pass 2b: 3-kernel exclusive scan over 262144 cell counts ----------------
__global__ __launch_bounds__(256) void scan_local(const int* __restrict__ cellhist,
                                                  int* __restrict__ cellstart,
                                                  int* __restrict__ chunksum) {
    __shared__ int ts[256];
    int t = threadIdx.x;
    int base = blockIdx.x * 1024 + t * 4;
    int4 v = *(const int4*)&cellhist[base];
    int s = v.x + v.y + v.z + v.w;
    ts[t] = s;
    __syncthreads();
    for (int d = 1; d < 256; d <<= 1) {
        int x = (t >= d) ? ts[t - d] : 0;
        __syncthreads();
        ts[t] += x;
        __syncthreads();
    }
    int excl = ts[t] - s;
    int4 o;
    o.x = excl; o.y = excl + v.x; o.z = o.y + v.y; o.w = o.z + v.z;
    *(int4*)&cellstart[base] = o;
    if (t == 255) chunksum[blockIdx.x] = ts[255];
}

__global__ __launch_bounds__(256) void scan_top(int* __restrict__ chunksum,
                                                int* __restrict__ cellstart) {
    __shared__ int ts[256];
    int t = threadIdx.x;
    int s = chunksum[t];
    ts[t] = s;
    __syncthreads();
    for (int d = 1; d < 256; d <<= 1) {
        int x = (t >= d) ? ts[t - d] : 0;
        __syncthreads();
        ts[t] += x;
        __syncthreads();
    }
    chunksum[t] = ts[t] - s;
    if (t == 255) cellstart[NCELL] = ts[255];
}

__global__ __launch_bounds__(256) void scan_add(int* __restrict__ cellstart,
                                                const int* __restrict__ chunksum) {
    int off = chunksum[blockIdx.x];
    if (off == 0) return;
    int base = blockIdx.x * 1024 + threadIdx.x * 4;
    int4 v = *(int4*)&cellstart[base];
    v.x += off; v.y += off; v.z += off; v.w += off;
    *(int4*)&cellstart[base] = v;
}

// ---------------- pass 3: scatter ids into z bins + cell-sorted positions ----------------
__global__ void scatter_kernel(const int* __restrict__ z_idx, const int* __restrict__ batch_idx,
                               const int* __restrict__ d0_idx, const int* __restrict__ d1_idx,
                               const int* __restrict__ pstart, int* __restrict__ cursors,
                               const int* __restrict__ cellstart, int* __restrict__ cellcur,
                               int* __restrict__ bins, int* __restrict__ segpos, int n) {
    __shared__ int lc[NZ];
    __shared__ int lbase[NZ];
    int t = threadIdx.x;
    if (t < NZ) lc[t] = 0;
    __syncthreads();
    int i = blockIdx.x * blockDim.x + t;
    int z = 0, rank = 0;
    bool valid = (i < n);
    if (valid) {
        z = z_idx[i]; z = z < 0 ? 0 : (z > NZ - 1 ? NZ - 1 : z);
        rank = atomicAdd(&lc[z], 1);
    }
    __syncthreads();
    if (t < NZ) lbase[t] = (lc[t] > 0) ? atomicAdd(&cursors[t], lc[t]) : 0;
    __syncthreads();
    if (valid) {
        int slot = pstart[z] + lbase[z] + rank;
        bins[slot] = i;
        int cell = (batch_idx[i] * HH + d0_idx[i]) * WWD + d1_idx[i];
        int r2 = atomicAdd(&cellcur[cell], 1);
        segpos[slot] = 1 + cellstart[cell] + r2;   // row 0 of bevf = dump for padding
    }
}

// ---------------- pass 4: bf16 MFMA GEMM per z-bin -> bf16 rows at cell-sorted pos ----------------
// LDS: Abf[128 p][64 k] + Wbf[128 c][64 k] bf16, XOR-swizzled (byte ^= (row&7)<<4).
// 4 waves; wave (wr,wc) computes a 64x64 tile via 32x mfma_f32_16x16x32_bf16.
// Epilogue: results staged as u16 into the SAME 32KB LDS ([128 p][128 ch], byte-xor
// ((prow>>2)&3)<<5, conflict-free), then 16 lanes x uint4 = one full 256B row per
// point per store instruction (R9's proven full-line store pattern).
__global__ __launch_bounds__(256) void gemm_kernel(
        const float* __restrict__ features, const float* __restrict__ kw,
        const float* __restrict__ bias,
        const int* __restrict__ pstart, const int* __restrict__ bins,
        const int* __restrict__ segpos, unsigned* __restrict__ bevf) {
    __shared__ __align__(16) char lbuf[32768];   // Abf+Wbf, then out-tile
    __shared__ int psl[PPB];
    char* Abf = lbuf;              // [128][64] bf16, swizzled
    char* Wbf = lbuf + 16384;      // [128][64] bf16, swizzled

    int start = blockIdx.x * PPB;
    int total = pstart[NZ];
    if (start >= total) return;
    int z = 0;
#pragma unroll
    for (int zz = 1; zz < NZ; ++zz)
        if (start >= pstart[zz]) z = zz;

    int tid = threadIdx.x;
    if (tid < PPB) psl[tid] = segpos[start + tid];

    {   // stage A: gather feature rows -> bf16 k-contig, swizzled b128 writes
        int r = tid >> 1, half = tid & 1;
        int raw = bins[start + r];
        int nid = raw < 0 ? 0 : raw;
        const float4* fp = (const float4*)(features + (size_t)nid * INC) + half * 8;
        float4 f[8];
#pragma unroll
        for (int q = 0; q < 8; ++q) f[q] = fp[q];
        unsigned u[16];
#pragma unroll
        for (int m = 0; m < 8; ++m) {
            u[2 * m]     = pack2(f[m].x, f[m].y);
            u[2 * m + 1] = pack2(f[m].z, f[m].w);
        }
#pragma unroll
        for (int ch = 0; ch < 4; ++ch) {
            int off = (r * 128 + half * 64 + ch * 16) ^ ((r & 7) << 4);
            uint4 val = make_uint4(u[4 * ch], u[4 * ch + 1], u[4 * ch + 2], u[4 * ch + 3]);
            *(uint4*)(Abf + off) = val;
        }
    }
    {   // stage W: per-lane column loads (coalesced across lanes, L1/L2-hot) -> bf16
        int c = tid & 127, kh = tid >> 7;
        const float* wp = kw + (size_t)z * INC * OUTC + c;
        float wv[32];
#pragma unroll
        for (int j = 0; j < 32; ++j) wv[j] = wp[(size_t)(kh * 32 + j) * OUTC];
        unsigned u[16];
#pragma unroll
        for (int m = 0; m < 16; ++m) u[m] = pack2(wv[2 * m], wv[2 * m + 1]);
#pragma unroll
        for (int ch = 0; ch < 4; ++ch) {
            int off = (c * 128 + kh * 64 + ch * 16) ^ ((c & 7) << 4);
            uint4 val = make_uint4(u[4 * ch], u[4 * ch + 1], u[4 * ch + 2], u[4 * ch + 3]);
            *(uint4*)(Wbf + off) = val;
        }
    }
    __syncthreads();

    int wv_ = tid >> 6, l = tid & 63;
    int wr = wv_ >> 1, wc = wv_ & 1;

    f32x4 acc[4][4];
#pragma unroll
    for (int i = 0; i < 4; ++i)
#pragma unroll
        for (int j = 0; j < 4; ++j) acc[i][j] = (f32x4){0.f, 0.f, 0.f, 0.f};

#pragma unroll
    for (int kc = 0; kc < 2; ++kc) {
        bf16x8 af[4], bfr[4];
#pragma unroll
        for (int pb = 0; pb < 4; ++pb) {
            int p = wr * 64 + pb * 16 + (l & 15);
            int off = (p * 128 + kc * 64 + (l >> 4) * 16) ^ ((p & 7) << 4);
            af[pb] = *(const bf16x8*)(Abf + off);
        }
#pragma unroll
        for (int cb = 0; cb < 4; ++cb) {
            int c = wc * 64 + cb * 16 + (l & 15);
            int off = (c * 128 + kc * 64 + (l >> 4) * 16) ^ ((c & 7) << 4);
            bfr[cb] = *(const bf16x8*)(Wbf + off);
        }
#pragma unroll
        for (int pb = 0; pb < 4; ++pb)
#pragma unroll
            for (int cb = 0; cb < 4; ++cb)
                acc[pb][cb] = __builtin_amdgcn_mfma_f32_16x16x32_bf16(
                    af[pb], bfr[cb], acc[pb][cb], 0, 0, 0);
    }
    __syncthreads();   // all Abf/Wbf reads complete; lbuf becomes the out-tile

    // epilogue stage 1: u16 bf16 writes into [128 p][128 ch] tile (256B rows),
    // byte-xor ((prow>>2)&3)<<5 -> every write instruction <=2 lanes/bank (free)
    float bias_c[4];
#pragma unroll
    for (int cb = 0; cb < 4; ++cb) bias_c[cb] = bias[wc * 64 + cb * 16 + (l & 15)];

#pragma unroll
    for (int pb = 0; pb < 4; ++pb) {
#pragma unroll
        for (int cb = 0; cb < 4; ++cb) {
            int c = wc * 64 + cb * 16 + (l & 15);
#pragma unroll
            for (int q = 0; q < 4; ++q) {
                int prow = wr * 64 + pb * 16 + (l >> 4) * 4 + q;
                float v = acc[pb][cb][q] + bias_c[cb];
                int byteoff = (prow * 256 + c * 2) ^ (((prow >> 2) & 3) << 5);
                *(unsigned short*)(lbuf + byteoff) = (unsigned short)bf16_rne(v);
            }
        }
    }
    __syncthreads();

    // epilogue stage 2: 16 lanes x uint4 = full 256B row per point (full-line stores)
#pragma unroll
    for (int j = 0; j < 8; ++j) {
        int s = j * 256 + tid;
        int prow = s >> 4, chunk = s & 15;
        int byteoff = (prow * 256 + chunk * 16) ^ (((prow >> 2) & 3) << 5);
        uint4 val = *(const uint4*)(lbuf + byteoff);
        int pos = psl[prow];
        *((uint4*)(bevf + (size_t)pos * 64) + chunk) = val;
    }
}

// ---------------- pass 5: register-accumulating per-row reduction (ZERO atomics) ----------------
__global__ __launch_bounds__(512) void reduce_kernel(
        const unsigned* __restrict__ bevf, const int* __restrict__ cellstart,
        float* __restrict__ out) {
    __shared__ unsigned tile[256 * 64];   // 64 KiB, [w][dword] rotate-swizzled by w
    int t = threadIdx.x;
    int blk = blockIdx.x;
    blk = (blk & 7) * (NSEG / 8) + (blk >> 3);   // XCD-contiguous segments
    int seg = blk;
    int wv = t >> 6, l = t & 63;

    int cell0 = seg * WWD + wv * 32;
    int cs_n = cellstart[cell0];
    int ce_n = cellstart[cell0 + 1];
    for (int j = 0; j < 32; ++j) {
        int cs = cs_n, ce = ce_n;
        cs_n = ce;
        if (j < 31) ce_n = cellstart[cell0 + j + 2];   // scalar prefetch
        float f0 = 0.f, f1 = 0.f;
        int k = cs;
        for (; k + 1 < ce; k += 2) {                   // 2 loads in flight
            unsigned v0 = bevf[(size_t)(k + 1) * 64 + l];
            unsigned v1 = bevf[(size_t)(k + 2) * 64 + l];
            f0 += __uint_as_float(v0 << 16);
            f1 += __uint_as_float(v0 & 0xFFFF0000u);
            f0 += __uint_as_float(v1 << 16);
            f1 += __uint_as_float(v1 & 0xFFFF0000u);
        }
        if (k < ce) {
            unsigned v0 = bevf[(size_t)(k + 1) * 64 + l];
            f0 += __uint_as_float(v0 << 16);
            f1 += __uint_as_float(v0 & 0xFFFF0000u);
        }
        int w = wv * 32 + j;
        tile[w * 64 + ((l + w) & 63)] = pack2(f0, f1);   // plain write, 2-way max (free)
    }
    __syncthreads();

    int b = seg >> 8, h = seg & 255;
    float* ob = out + (size_t)b * OUTC * HWD + (size_t)h * WWD;
#pragma unroll
    for (int r = 0; r < 16; ++r) {
        int c = wv + 8 * r;        // 0..127
        int d = c >> 1;            // dword index (ch pair 2d,2d+1)
        float* op = ob + (size_t)c * HWD;
#pragma unroll
        for (int q = 0; q < 4; ++q) {
            int w = 64 * q + l;
            unsigned v = tile[w * 64 + ((d + w) & 63)];
            op[w] = __uint_as_float((c & 1) ? (v & 0xFFFF0000u) : (v << 16));
        }
    }
}

// ---------------- fallback (ws too small): direct scattered atomics into BCHW ----------------
__global__ __launch_bounds__(256) void naive_kernel(
        const float* __restrict__ features, const float* __restrict__ kw,
        const float* __restrict__ bias,
        const int* __restrict__ bidx, const int* __restrict__ d0,
        const int* __restrict__ d1, const int* __restrict__ zi,
        float* __restrict__ out, int n) {
    long long gid = (long long)blockIdx.x * blockDim.x + threadIdx.x;
    int pid = (int)(gid >> 7);
    int c   = (int)(gid & (OUTC - 1));
    if (pid >= n) return;
    int z = zi[pid]; z = z < 0 ? 0 : (z > NZ - 1 ? NZ - 1 : z);
    const float4* fp = (const float4*)(features + (size_t)pid * INC);
    const float* wp = kw + (size_t)z * INC * OUTC + c;
    float a0 = bias[c], a1 = 0.f, a2 = 0.f, a3 = 0.f;
#pragma unroll
    for (int i = 0; i < INC / 4; ++i) {
        float4 f = fp[i];
        a0 += f.x * wp[(size_t)(4 * i + 0) * OUTC];
        a1 += f.y * wp[(size_t)(4 * i + 1) * OUTC];
        a2 += f.z * wp[(size_t)(4 * i + 2) * OUTC];
        a3 += f.w * wp[(size_t)(4 * i + 3) * OUTC];
    }
    float acc = (a0 + a1) + (a2 + a3);
    size_t oidx = ((size_t)bidx[pid] * OUTC + c) * HWD + (size_t)d0[pid] * WWD + d1[pid];
    unsafeAtomicAdd(&out[oidx], acc);
}

extern "C" void kernel_launch(void* const* d_in, const int* in_sizes, int n_in,
                              void* d_out, int out_size, void* d_ws, size_t ws_size,
                              hipStream_t stream) {
    const float* features = (const float*)d_in[0];
    const float* kw       = (const float*)d_in[1];
    const float* bias     = (const float*)d_in[2];
    const int* batch_idx  = (const int*)d_in[3];
    const int* d0_idx     = (const int*)d_in[4];
    const int* d1_idx     = (const int*)d_in[5];
    const int* z_idx      = (const int*)d_in[6];
    float* out = (float*)d_out;
    int n = in_sizes[0] / INC;   // number of points

    size_t binsElems = (size_t)n + (size_t)NZ * PPB;
    size_t bevfBytes = (binsElems + 1) * OUTC * 2;           // ~77.5 MB
    size_t metaOff   = (bevfBytes + 255) & ~(size_t)255;
    size_t chOff     = metaOff + 32 * 4;                     // cellhist
    size_t ccOff     = chOff + (size_t)NCELL * 4;            // cellcur
    size_t csOff     = ccOff + (size_t)NCELL * 4;            // cellstart (NCELL+1)
    size_t ckOff     = csOff + (size_t)(NCELL + 4) * 4;      // chunksum (256)
    size_t binsOff   = (ckOff + 256 * 4 + 255) & ~(size_t)255;
    size_t posOff    = binsOff + binsElems * 4;
    size_t need      = posOff + binsElems * 4 + 16;

    if (ws_size >= need) {
        char* ws = (char*)d_ws;
        unsigned* bevf = (unsigned*)ws;
        int* meta      = (int*)(ws + metaOff);   // counts[8], cursors[8], pstart[9]
        int* counts    = meta;
        int* cursors   = meta + 8;
        int* pstart    = meta + 16;
        int* cellhist  = (int*)(ws + chOff);
        int* cellcur   = (int*)(ws + ccOff);
        int* cellstart = (int*)(ws + csOff);
        int* chunksum  = (int*)(ws + ckOff);
        int* bins      = (int*)(ws + binsOff);
        int* segpos    = (int*)(ws + posOff);

        hipMemsetAsync(meta, 0, 32 * 4, stream);
        hipMemsetAsync(cellhist, 0, (size_t)NCELL * 4, stream);
        hipMemsetAsync(cellcur, 0, (size_t)NCELL * 4, stream);
        hipMemsetAsync(bins, 0xFF, binsElems * 4, stream);   // -1 padding
        hipMemsetAsync(segpos, 0, binsElems * 4, stream);    // padding -> dump row 0

        int gb = (n + 255) / 256;
        hist_kernel<<<gb, 256, 0, stream>>>(z_idx, batch_idx, d0_idx, d1_idx,
                                            counts, cellhist, n);
        prefix_z_kernel<<<1, 64, 0, stream>>>(counts, pstart);
        scan_local<<<256, 256, 0, stream>>>(cellhist, cellstart, chunksum);
        scan_top<<<1, 256, 0, stream>>>(chunksum, cellstart);
        scan_add<<<256, 256, 0, stream>>>(cellstart, chunksum);
        scatter_kernel<<<gb, 256, 0, stream>>>(z_idx, batch_idx, d0_idx, d1_idx,
                                               pstart, cursors, cellstart, cellcur,
                                               bins, segpos, n);

        int nblk = (int)((binsElems + PPB - 1) / PPB) + 1;
        gemm_kernel<<<nblk, 256, 0, stream>>>(features, kw, bias, pstart, bins,
                                              segpos, bevf);

        reduce_kernel<<<NSEG, 512, 0, stream>>>(bevf, cellstart, out);
    } else {
        hipMemsetAsync(out, 0, (size_t)out_size * sizeof(float), stream);
        long long threads = (long long)n * OUTC;
        int gb = (int)((threads + 255) / 256);
        naive_kernel<<<gb, 256, 0, stream>>>(features, kw, bias, batch_idx, d0_idx,
                                             d1_idx, z_idx, out, n);
    }
}

// Round 12
// 154.527 us; speedup vs baseline: 1.4095x; 1.1212x over previous
//
#include <hip/hip_runtime.h>

#define PPB   128
#define NZ    8
#define INC   64
#define OUTC  128
#define NB    4
#define HH    256
#define WWD   256
#define HWD   (HH * WWD)
#define NSEG  (NB * HH)          // 1024 row segments (b*HH + h)
#define NCELL (NB * HH * WWD)    // 262144 cells (flat bev index)

typedef __attribute__((ext_vector_type(8))) short bf16x8;
typedef __attribute__((ext_vector_type(4))) float f32x4;

__device__ __forceinline__ unsigned bf16_rne(float x) {
    unsigned u = __float_as_uint(x);
    return (u + 0x7FFFu + ((u >> 16) & 1u)) >> 16;
}
__device__ __forceinline__ unsigned pack2(float lo, float hi) {
    return bf16_rne(lo) | (bf16_rne(hi) << 16);
}

// ---------------- pass 0: one-time W transpose to bf16 [z][c][k] ----------------
__global__ __launch_bounds__(256) void wprep_kernel(const float* __restrict__ kw,
                                                    unsigned short* __restrict__ wt) {
    int z = blockIdx.x;
    const float* src = kw + (size_t)z * INC * OUTC;    // [k][c] fp32
    unsigned short* dst = wt + (size_t)z * OUTC * INC; // [c][k] bf16
    int t = threadIdx.x;
    for (int c = t; c < OUTC; c += 256) {
#pragma unroll
        for (int k = 0; k < INC; k += 2) {
            float a = src[(size_t)k * OUTC + c];
            float b = src[(size_t)(k + 1) * OUTC + c];
            *(unsigned*)&dst[(size_t)c * INC + k] = pack2(a, b);
        }
    }
}

// ---------------- pass 1: z histogram + cell histogram ----------------
__global__ void hist_kernel(const int* __restrict__ z_idx, const int* __restrict__ batch_idx,
                            const int* __restrict__ d0_idx, const int* __restrict__ d1_idx,
                            int* __restrict__ counts, int* __restrict__ cellhist, int n) {
    __shared__ int lc[NZ];
    int t = threadIdx.x;
    if (t < NZ) lc[t] = 0;
    __syncthreads();
    int i = blockIdx.x * blockDim.x + t;
    if (i < n) {
        int z = z_idx[i]; z = z < 0 ? 0 : (z > NZ - 1 ? NZ - 1 : z);
        atomicAdd(&lc[z], 1);
        int cell = (batch_idx[i] * HH + d0_idx[i]) * WWD + d1_idx[i];
        atomicAdd(&cellhist[cell], 1);
    }
    __syncthreads();
    if (t < NZ && lc[t] > 0) atomicAdd(&counts[t], lc[t]);
}

// ---------------- pass 2: 3-kernel exclusive scan over 262144 cell counts (+z prefix) ----------------
__global__ __launch_bounds__(256) void scan_local(const int* __restrict__ cellhist,
                                                  int* __restrict__ cellstart,
                                                  int* __restrict__ chunksum) {
    __shared__ int ts[256];
    int t = threadIdx.x;
    int base = blockIdx.x * 1024 + t * 4;
    int4 v = *(const int4*)&cellhist[base];
    int s = v.x + v.y + v.z + v.w;
    ts[t] = s;
    __syncthreads();
    for (int d = 1; d < 256; d <<= 1) {
        int x = (t >= d) ? ts[t - d] : 0;
        __syncthreads();
        ts[t] += x;
        __syncthreads();
    }
    int excl = ts[t] - s;
    int4 o;
    o.x = excl; o.y = excl + v.x; o.z = o.y + v.y; o.w = o.z + v.z;
    *(int4*)&cellstart[base] = o;
    if (t == 255) chunksum[blockIdx.x] = ts[255];
}

__global__ __launch_bounds__(256) void scan_top(int* __restrict__ chunksum,
                                                const int* __restrict__ counts,
                                                int* __restrict__ pstart) {
    __shared__ int ts[256];
    int t = threadIdx.x;
    if (t == 0) {   // folded z-bin padded prefix
        int off = 0;
        for (int z = 0; z < NZ; ++z) {
            pstart[z] = off;
            off += ((counts[z] + PPB - 1) / PPB) * PPB;
        }
        pstart[NZ] = off;
    }
    int s = chunksum[t];
    ts[t] = s;
    __syncthreads();
    for (int d = 1; d < 256; d <<= 1) {
        int x = (t >= d) ? ts[t - d] : 0;
        __syncthreads();
        ts[t] += x;
        __syncthreads();
    }
    chunksum[t] = ts[t] - s;
}

__global__ __launch_bounds__(256) void scan_add(int* __restrict__ cellstart,
                                                const int* __restrict__ chunksum) {
    int off = chunksum[blockIdx.x];
    if (off == 0) return;
    int base = blockIdx.x * 1024 + threadIdx.x * 4;
    int4 v = *(int4*)&cellstart[base];
    v.x += off; v.y += off; v.z += off; v.w += off;
    *(int4*)&cellstart[base] = v;
}

// ---------------- pass 2c: fill only the padding slots (replaces 2.4MB of memsets) ----------------
__global__ void pad_kernel(const int* __restrict__ counts, const int* __restrict__ pstart,
                           int* __restrict__ bins, int* __restrict__ segpos) {
    int z = blockIdx.x;                    // 0..7
    int cnt = counts[z];
    int s0 = pstart[z];
    int padded = pstart[z + 1] - s0;
    for (int i = cnt + threadIdx.x; i < padded; i += blockDim.x) {
        bins[s0 + i] = -1;
        segpos[s0 + i] = 0;                // dump row
    }
}

// ---------------- pass 3: scatter ids into z bins + cell-sorted positions ----------------
// Mutates cellstart in place: after completion, cellstart[c] == orig[c+1].
__global__ void scatter_kernel(const int* __restrict__ z_idx, const int* __restrict__ batch_idx,
                               const int* __restrict__ d0_idx, const int* __restrict__ d1_idx,
                               const int* __restrict__ pstart, int* __restrict__ cursors,
                               int* __restrict__ cellstart,
                               int* __restrict__ bins, int* __restrict__ segpos, int n) {
    __shared__ int lc[NZ];
    __shared__ int lbase[NZ];
    int t = threadIdx.x;
    if (t < NZ) lc[t] = 0;
    __syncthreads();
    int i = blockIdx.x * blockDim.x + t;
    int z = 0, rank = 0;
    bool valid = (i < n);
    if (valid) {
        z = z_idx[i]; z = z < 0 ? 0 : (z > NZ - 1 ? NZ - 1 : z);
        rank = atomicAdd(&lc[z], 1);
    }
    __syncthreads();
    if (t < NZ) lbase[t] = (lc[t] > 0) ? atomicAdd(&cursors[t], lc[t]) : 0;
    __syncthreads();
    if (valid) {
        int slot = pstart[z] + lbase[z] + rank;
        bins[slot] = i;
        int cell = (batch_idx[i] * HH + d0_idx[i]) * WWD + d1_idx[i];
        int r2 = atomicAdd(&cellstart[cell], 1);   // returns cell-sorted position
        segpos[slot] = 1 + r2;                     // row 0 of bevf = dump
    }
}

// ---------------- pass 4: bf16 MFMA GEMM per z-bin -> bf16 rows at cell-sorted pos ----------------
__global__ __launch_bounds__(256) void gemm_kernel(
        const float* __restrict__ features, const unsigned short* __restrict__ wt,
        const float* __restrict__ bias,
        const int* __restrict__ pstart, const int* __restrict__ bins,
        const int* __restrict__ segpos, unsigned* __restrict__ bevf) {
    __shared__ __align__(16) char lbuf[32768];   // Abf+Wbf, then out-tile
    __shared__ int psl[PPB];
    char* Abf = lbuf;              // [128 p][64 k] bf16, swizzled
    char* Wbf = lbuf + 16384;      // [128 c][64 k] bf16, swizzled

    int start = blockIdx.x * PPB;
    int total = pstart[NZ];
    if (start >= total) return;
    int z = 0;
#pragma unroll
    for (int zz = 1; zz < NZ; ++zz)
        if (start >= pstart[zz]) z = zz;

    int tid = threadIdx.x;
    if (tid < PPB) psl[tid] = segpos[start + tid];

    {   // stage A: gather feature rows -> bf16 k-contig, swizzled b128 writes
        int r = tid >> 1, half = tid & 1;
        int raw = bins[start + r];
        int nid = raw < 0 ? 0 : raw;
        const float4* fp = (const float4*)(features + (size_t)nid * INC) + half * 8;
        float4 f[8];
#pragma unroll
        for (int q = 0; q < 8; ++q) f[q] = fp[q];
        unsigned u[16];
#pragma unroll
        for (int m = 0; m < 8; ++m) {
            u[2 * m]     = pack2(f[m].x, f[m].y);
            u[2 * m + 1] = pack2(f[m].z, f[m].w);
        }
#pragma unroll
        for (int ch = 0; ch < 4; ++ch) {
            int off = (r * 128 + half * 64 + ch * 16) ^ ((r & 7) << 4);
            uint4 val = make_uint4(u[4 * ch], u[4 * ch + 1], u[4 * ch + 2], u[4 * ch + 3]);
            *(uint4*)(Abf + off) = val;
        }
    }
    {   // stage W: coalesced 16KB copy of pre-transposed bf16 Wt[z] ([c][k])
        const uint4* src = (const uint4*)(wt + (size_t)z * OUTC * INC);
#pragma unroll
        for (int i = 0; i < 4; ++i) {
            int s = tid + 256 * i;            // uint4 idx: c = s>>3, chunk = s&7
            int c = s >> 3, ch = s & 7;
            int off = (c * 128 + ch * 16) ^ ((c & 7) << 4);
            *(uint4*)(Wbf + off) = src[s];
        }
    }
    __syncthreads();

    int wv_ = tid >> 6, l = tid & 63;
    int wr = wv_ >> 1, wc = wv_ & 1;

    f32x4 acc[4][4];
#pragma unroll
    for (int i = 0; i < 4; ++i)
#pragma unroll
        for (int j = 0; j < 4; ++j) acc[i][j] = (f32x4){0.f, 0.f, 0.f, 0.f};

#pragma unroll
    for (int kc = 0; kc < 2; ++kc) {
        bf16x8 af[4], bfr[4];
#pragma unroll
        for (int pb = 0; pb < 4; ++pb) {
            int p = wr * 64 + pb * 16 + (l & 15);
            int off = (p * 128 + kc * 64 + (l >> 4) * 16) ^ ((p & 7) << 4);
            af[pb] = *(const bf16x8*)(Abf + off);
        }
#pragma unroll
        for (int cb = 0; cb < 4; ++cb) {
            int c = wc * 64 + cb * 16 + (l & 15);
            int off = (c * 128 + kc * 64 + (l >> 4) * 16) ^ ((c & 7) << 4);
            bfr[cb] = *(const bf16x8*)(Wbf + off);
        }
#pragma unroll
        for (int pb = 0; pb < 4; ++pb)
#pragma unroll
            for (int cb = 0; cb < 4; ++cb)
                acc[pb][cb] = __builtin_amdgcn_mfma_f32_16x16x32_bf16(
                    af[pb], bfr[cb], acc[pb][cb], 0, 0, 0);
    }
    __syncthreads();   // Abf/Wbf reads complete; lbuf becomes the out-tile

    // epilogue stage 1: u16 bf16 writes into [128 p][128 ch] tile
    float bias_c[4];
#pragma unroll
    for (int cb = 0; cb < 4; ++cb) bias_c[cb] = bias[wc * 64 + cb * 16 + (l & 15)];

#pragma unroll
    for (int pb = 0; pb < 4; ++pb) {
#pragma unroll
        for (int cb = 0; cb < 4; ++cb) {
            int c = wc * 64 + cb * 16 + (l & 15);
#pragma unroll
            for (int q = 0; q < 4; ++q) {
                int prow = wr * 64 + pb * 16 + (l >> 4) * 4 + q;
                float v = acc[pb][cb][q] + bias_c[cb];
                int byteoff = (prow * 256 + c * 2) ^ (((prow >> 2) & 3) << 5);
                *(unsigned short*)(lbuf + byteoff) = (unsigned short)bf16_rne(v);
            }
        }
    }
    __syncthreads();

    // epilogue stage 2: 16 lanes x uint4 = full 256B row per point
#pragma unroll
    for (int j = 0; j < 8; ++j) {
        int s = j * 256 + tid;
        int prow = s >> 4, chunk = s & 15;
        int byteoff = (prow * 256 + chunk * 16) ^ (((prow >> 2) & 3) << 5);
        uint4 val = *(const uint4*)(lbuf + byteoff);
        int pos = psl[prow];
        *((uint4*)(bevf + (size_t)pos * 64) + chunk) = val;
    }
}

// ---------------- pass 5: streaming register reduction (zero atomics, dense row loads) ----------------
// cellstart is MUTATED: mut[c] = orig[c+1]. Wave wv owns cells [cell0, cell0+32);
// lane i<=32 preloads orig[cell0+i] = mut[cell0+i-1]; boundaries walked in registers
// via __shfl -> bevf row loads are dense/affine and pipeline 4-deep.
__global__ __launch_bounds__(512) void reduce_kernel(
        const unsigned* __restrict__ bevf, const int* __restrict__ cellstart,
        float* __restrict__ out) {
    __shared__ unsigned tile[256 * 64];   // 64 KiB, [w][dword] rotate-swizzled
    int t = threadIdx.x;
    int blk = blockIdx.x;
    blk = (blk & 7) * (NSEG / 8) + (blk >> 3);   // XCD-contiguous segments
    int seg = blk;
    int wv = t >> 6, l = t & 63;

    int cell0 = seg * WWD + wv * 32;
    int idx = cell0 + l - 1;
    int bound = 0;
    if (l <= 32) bound = (idx < 0) ? 0 : cellstart[idx];   // lane i: orig[cell0+i]
    int r0 = __shfl(bound, 0);
    int r1 = __shfl(bound, 32);

    int j = 0;
    int ce = __shfl(bound, 1);
    float f0 = 0.f, f1 = 0.f;
    for (int r = r0; r < r1; r += 4) {
        unsigned v[4];
#pragma unroll
        for (int u = 0; u < 4; ++u) {
            int rr = (r + u < r1) ? r + u : r1 - 1;
            v[u] = bevf[(size_t)(rr + 1) * 64 + l];    // dense 256B/wave stream
        }
#pragma unroll
        for (int u = 0; u < 4; ++u) {
            if (r + u >= r1) break;
            while (r + u >= ce) {                      // wave-uniform cell advance
                int w = wv * 32 + j;
                tile[w * 64 + ((l + w) & 63)] = pack2(f0, f1);
                f0 = 0.f; f1 = 0.f;
                ++j;
                ce = __shfl(bound, j + 1);
            }
            f0 += __uint_as_float(v[u] << 16);
            f1 += __uint_as_float(v[u] & 0xFFFF0000u);
        }
    }
    while (j < 32) {                                   // flush tail (+empty cells)
        int w = wv * 32 + j;
        tile[w * 64 + ((l + w) & 63)] = pack2(f0, f1);
        f0 = 0.f; f1 = 0.f;
        ++j;
    }
    __syncthreads();

    int b = seg >> 8, h = seg & 255;
    float* ob = out + (size_t)b * OUTC * HWD + (size_t)h * WWD;
#pragma unroll
    for (int r = 0; r < 16; ++r) {
        int c = wv + 8 * r;
        int d = c >> 1;
        float* op = ob + (size_t)c * HWD;
#pragma unroll
        for (int q = 0; q < 4; ++q) {
            int w = 64 * q + l;
            unsigned v = tile[w * 64 + ((d + w) & 63)];
            op[w] = __uint_as_float((c & 1) ? (v & 0xFFFF0000u) : (v << 16));
        }
    }
}

// ---------------- fallback (ws too small): direct scattered atomics into BCHW ----------------
__global__ __launch_bounds__(256) void naive_kernel(
        const float* __restrict__ features, const float* __restrict__ kw,
        const float* __restrict__ bias,
        const int* __restrict__ bidx, const int* __restrict__ d0,
        const int* __restrict__ d1, const int* __restrict__ zi,
        float* __restrict__ out, int n) {
    long long gid = (long long)blockIdx.x * blockDim.x + threadIdx.x;
    int pid = (int)(gid >> 7);
    int c   = (int)(gid & (OUTC - 1));
    if (pid >= n) return;
    int z = zi[pid]; z = z < 0 ? 0 : (z > NZ - 1 ? NZ - 1 : z);
    const float4* fp = (const float4*)(features + (size_t)pid * INC);
    const float* wp = kw + (size_t)z * INC * OUTC + c;
    float a0 = bias[c], a1 = 0.f, a2 = 0.f, a3 = 0.f;
#pragma unroll
    for (int i = 0; i < INC / 4; ++i) {
        float4 f = fp[i];
        a0 += f.x * wp[(size_t)(4 * i + 0) * OUTC];
        a1 += f.y * wp[(size_t)(4 * i + 1) * OUTC];
        a2 += f.z * wp[(size_t)(4 * i + 2) * OUTC];
        a3 += f.w * wp[(size_t)(4 * i + 3) * OUTC];
    }
    float acc = (a0 + a1) + (a2 + a3);
    size_t oidx = ((size_t)bidx[pid] * OUTC + c) * HWD + (size_t)d0[pid] * WWD + d1[pid];
    unsafeAtomicAdd(&out[oidx], acc);
}

extern "C" void kernel_launch(void* const* d_in, const int* in_sizes, int n_in,
                              void* d_out, int out_size, void* d_ws, size_t ws_size,
                              hipStream_t stream) {
    const float* features = (const float*)d_in[0];
    const float* kw       = (const float*)d_in[1];
    const float* bias     = (const float*)d_in[2];
    const int* batch_idx  = (const int*)d_in[3];
    const int* d0_idx     = (const int*)d_in[4];
    const int* d1_idx     = (const int*)d_in[5];
    const int* z_idx      = (const int*)d_in[6];
    float* out = (float*)d_out;
    int n = in_sizes[0] / INC;   // number of points

    size_t binsElems = (size_t)n + (size_t)NZ * PPB;
    size_t bevfBytes = (binsElems + 1) * OUTC * 2;           // ~77.5 MB
    size_t wtOff     = (bevfBytes + 255) & ~(size_t)255;     // bf16 Wt: 128 KiB
    size_t metaOff   = wtOff + (size_t)NZ * OUTC * INC * 2;
    size_t chOff     = (metaOff + 32 * 4 + 255) & ~(size_t)255;   // cellhist
    size_t csOff     = chOff + (size_t)NCELL * 4;            // cellstart (NCELL+4)
    size_t ckOff     = csOff + (size_t)(NCELL + 4) * 4;      // chunksum (256)
    size_t binsOff   = (ckOff + 256 * 4 + 255) & ~(size_t)255;
    size_t posOff    = binsOff + binsElems * 4;
    size_t need      = posOff + binsElems * 4 + 16;

    if (ws_size >= need) {
        char* ws = (char*)d_ws;
        unsigned* bevf = (unsigned*)ws;
        unsigned short* wt = (unsigned short*)(ws + wtOff);
        int* meta      = (int*)(ws + metaOff);   // counts[8], cursors[8], pstart[9]
        int* counts    = meta;
        int* cursors   = meta + 8;
        int* pstart    = meta + 16;
        int* cellhist  = (int*)(ws + chOff);
        int* cellstart = (int*)(ws + csOff);
        int* chunksum  = (int*)(ws + ckOff);
        int* bins      = (int*)(ws + binsOff);
        int* segpos    = (int*)(ws + posOff);

        hipMemsetAsync(meta, 0, 32 * 4, stream);
        hipMemsetAsync(cellhist, 0, (size_t)NCELL * 4, stream);

        int gb = (n + 255) / 256;
        wprep_kernel<<<NZ, 256, 0, stream>>>(kw, wt);
        hist_kernel<<<gb, 256, 0, stream>>>(z_idx, batch_idx, d0_idx, d1_idx,
                                            counts, cellhist, n);
        scan_local<<<256, 256, 0, stream>>>(cellhist, cellstart, chunksum);
        scan_top<<<1, 256, 0, stream>>>(chunksum, counts, pstart);
        scan_add<<<256, 256, 0, stream>>>(cellstart, chunksum);
        pad_kernel<<<NZ, 128, 0, stream>>>(counts, pstart, bins, segpos);
        scatter_kernel<<<gb, 256, 0, stream>>>(z_idx, batch_idx, d0_idx, d1_idx,
                                               pstart, cursors, cellstart,
                                               bins, segpos, n);

        int nblk = (int)((binsElems + PPB - 1) / PPB) + 1;
        gemm_kernel<<<nblk, 256, 0, stream>>>(features, wt, bias, pstart, bins,
                                              segpos, bevf);

        reduce_kernel<<<NSEG, 512, 0, stream>>>(bevf, cellstart, out);
    } else {
        hipMemsetAsync(out, 0, (size_t)out_size * sizeof(float), stream);
        long long threads = (long long)n * OUTC;
        int gb = (int)((threads + 255) / 256);
        naive_kernel<<<gb, 256, 0, stream>>>(features, kw, bias, batch_idx, d0_idx,
                                             d1_idx, z_idx, out, n);
    }
}

// Round 13
// 152.455 us; speedup vs baseline: 1.4287x; 1.0136x over previous
//
#include <hip/hip_runtime.h>

#define PPB   128
#define NZ    8
#define INC   64
#define OUTC  128
#define NB    4
#define HH    256
#define WWD   256
#define HWD   (HH * WWD)
#define NSEG  (NB * HH)          // 1024 row segments (b*HH + h)
#define NCELL (NB * HH * WWD)    // 262144 cells (flat bev index)

typedef __attribute__((ext_vector_type(8))) short bf16x8;
typedef __attribute__((ext_vector_type(4))) float f32x4;

__device__ __forceinline__ unsigned bf16_rne(float x) {
    unsigned u = __float_as_uint(x);
    return (u + 0x7FFFu + ((u >> 16) & 1u)) >> 16;
}
__device__ __forceinline__ unsigned pack2(float lo, float hi) {
    return bf16_rne(lo) | (bf16_rne(hi) << 16);
}

// ---------------- pass 0: one-time W transpose to bf16 [z][c][k] ----------------
__global__ __launch_bounds__(256) void wprep_kernel(const float* __restrict__ kw,
                                                    unsigned short* __restrict__ wt) {
    int z = blockIdx.x;
    const float* src = kw + (size_t)z * INC * OUTC;    // [k][c] fp32
    unsigned short* dst = wt + (size_t)z * OUTC * INC; // [c][k] bf16
    int t = threadIdx.x;
    for (int c = t; c < OUTC; c += 256) {
#pragma unroll
        for (int k = 0; k < INC; k += 2) {
            float a = src[(size_t)k * OUTC + c];
            float b = src[(size_t)(k + 1) * OUTC + c];
            *(unsigned*)&dst[(size_t)c * INC + k] = pack2(a, b);
        }
    }
}

// ---------------- pass 1: z histogram + cell histogram ----------------
__global__ void hist_kernel(const int* __restrict__ z_idx, const int* __restrict__ batch_idx,
                            const int* __restrict__ d0_idx, const int* __restrict__ d1_idx,
                            int* __restrict__ counts, int* __restrict__ cellhist, int n) {
    __shared__ int lc[NZ];
    int t = threadIdx.x;
    if (t < NZ) lc[t] = 0;
    __syncthreads();
    int i = blockIdx.x * blockDim.x + t;
    if (i < n) {
        int z = z_idx[i]; z = z < 0 ? 0 : (z > NZ - 1 ? NZ - 1 : z);
        atomicAdd(&lc[z], 1);
        int cell = (batch_idx[i] * HH + d0_idx[i]) * WWD + d1_idx[i];
        atomicAdd(&cellhist[cell], 1);
    }
    __syncthreads();
    if (t < NZ && lc[t] > 0) atomicAdd(&counts[t], lc[t]);
}

// ---------------- pass 2a: local exclusive scan per 1024-chunk (+z padded prefix) ----------------
__global__ __launch_bounds__(256) void scan_local(const int* __restrict__ cellhist,
                                                  int* __restrict__ cellstart,
                                                  int* __restrict__ chunksum,
                                                  const int* __restrict__ counts,
                                                  int* __restrict__ pstart) {
    if (blockIdx.x == 0 && threadIdx.x == 0) {   // folded z-bin padded prefix
        int off = 0;
        for (int z = 0; z < NZ; ++z) {
            pstart[z] = off;
            off += ((counts[z] + PPB - 1) / PPB) * PPB;
        }
        pstart[NZ] = off;
    }
    __shared__ int ts[256];
    int t = threadIdx.x;
    int base = blockIdx.x * 1024 + t * 4;
    int4 v = *(const int4*)&cellhist[base];
    int s = v.x + v.y + v.z + v.w;
    ts[t] = s;
    __syncthreads();
    for (int d = 1; d < 256; d <<= 1) {
        int x = (t >= d) ? ts[t - d] : 0;
        __syncthreads();
        ts[t] += x;
        __syncthreads();
    }
    int excl = ts[t] - s;
    int4 o;
    o.x = excl; o.y = excl + v.x; o.z = o.y + v.y; o.w = o.z + v.z;
    *(int4*)&cellstart[base] = o;
    if (t == 255) chunksum[blockIdx.x] = ts[255];
}

// ---------------- pass 2b: each block sums prior chunksums itself and adds ----------------
__global__ __launch_bounds__(256) void scan_add2(int* __restrict__ cellstart,
                                                 const int* __restrict__ chunksum) {
    __shared__ int ts[256];
    int t = threadIdx.x;
    int b = blockIdx.x;
    ts[t] = (t < b) ? chunksum[t] : 0;
    __syncthreads();
    for (int d = 128; d > 0; d >>= 1) {
        if (t < d) ts[t] += ts[t + d];
        __syncthreads();
    }
    int off = ts[0];
    if (off == 0) return;
    int base = b * 1024 + t * 4;
    int4 v = *(int4*)&cellstart[base];
    v.x += off; v.y += off; v.z += off; v.w += off;
    *(int4*)&cellstart[base] = v;
}

// ---------------- pass 3: scatter ids into z bins + cell-sorted positions ----------------
// Mutates cellstart in place: after completion, cellstart[c] == orig[c+1].
__global__ void scatter_kernel(const int* __restrict__ z_idx, const int* __restrict__ batch_idx,
                               const int* __restrict__ d0_idx, const int* __restrict__ d1_idx,
                               const int* __restrict__ pstart, int* __restrict__ cursors,
                               int* __restrict__ cellstart,
                               int* __restrict__ bins, int* __restrict__ segpos, int n) {
    __shared__ int lc[NZ];
    __shared__ int lbase[NZ];
    int t = threadIdx.x;
    if (t < NZ) lc[t] = 0;
    __syncthreads();
    int i = blockIdx.x * blockDim.x + t;
    int z = 0, rank = 0;
    bool valid = (i < n);
    if (valid) {
        z = z_idx[i]; z = z < 0 ? 0 : (z > NZ - 1 ? NZ - 1 : z);
        rank = atomicAdd(&lc[z], 1);
    }
    __syncthreads();
    if (t < NZ) lbase[t] = (lc[t] > 0) ? atomicAdd(&cursors[t], lc[t]) : 0;
    __syncthreads();
    if (valid) {
        int slot = pstart[z] + lbase[z] + rank;
        bins[slot] = i;
        int cell = (batch_idx[i] * HH + d0_idx[i]) * WWD + d1_idx[i];
        int r2 = atomicAdd(&cellstart[cell], 1);   // returns cell-sorted position
        segpos[slot] = 1 + r2;                     // row 0 of bevf = dump
    }
}

// ---------------- pass 4: bf16 MFMA GEMM per z-bin -> bf16 rows at cell-sorted pos ----------------
// Padding handled arithmetically: slots >= pstart[z]+counts[z] are masked (no pad_kernel).
__global__ __launch_bounds__(256) void gemm_kernel(
        const float* __restrict__ features, const unsigned short* __restrict__ wt,
        const float* __restrict__ bias, const int* __restrict__ counts,
        const int* __restrict__ pstart, const int* __restrict__ bins,
        const int* __restrict__ segpos, unsigned* __restrict__ bevf) {
    __shared__ __align__(16) char lbuf[32768];   // Abf+Wbf, then out-tile
    __shared__ int psl[PPB];
    char* Abf = lbuf;              // [128 p][64 k] bf16, swizzled
    char* Wbf = lbuf + 16384;      // [128 c][64 k] bf16, swizzled

    int start = blockIdx.x * PPB;
    int total = pstart[NZ];
    if (start >= total) return;
    int z = 0;
#pragma unroll
    for (int zz = 1; zz < NZ; ++zz)
        if (start >= pstart[zz]) z = zz;
    int limit = pstart[z] + counts[z] - start;   // slots [0,limit) are real points
    if (limit <= 0) return;                      // fully-padded block

    int tid = threadIdx.x;
    if (tid < PPB) psl[tid] = (tid < limit) ? segpos[start + tid] : 0;   // pad -> dump

    {   // stage A: gather feature rows -> bf16 k-contig, swizzled b128 writes
        int r = tid >> 1, half = tid & 1;
        int raw = (r < limit) ? bins[start + r] : 0;
        int nid = raw < 0 ? 0 : raw;
        const float4* fp = (const float4*)(features + (size_t)nid * INC) + half * 8;
        float4 f[8];
#pragma unroll
        for (int q = 0; q < 8; ++q) f[q] = fp[q];
        unsigned u[16];
#pragma unroll
        for (int m = 0; m < 8; ++m) {
            u[2 * m]     = pack2(f[m].x, f[m].y);
            u[2 * m + 1] = pack2(f[m].z, f[m].w);
        }
#pragma unroll
        for (int ch = 0; ch < 4; ++ch) {
            int off = (r * 128 + half * 64 + ch * 16) ^ ((r & 7) << 4);
            uint4 val = make_uint4(u[4 * ch], u[4 * ch + 1], u[4 * ch + 2], u[4 * ch + 3]);
            *(uint4*)(Abf + off) = val;
        }
    }
    {   // stage W: coalesced 16KB copy of pre-transposed bf16 Wt[z] ([c][k])
        const uint4* src = (const uint4*)(wt + (size_t)z * OUTC * INC);
#pragma unroll
        for (int i = 0; i < 4; ++i) {
            int s = tid + 256 * i;
            int c = s >> 3, ch = s & 7;
            int off = (c * 128 + ch * 16) ^ ((c & 7) << 4);
            *(uint4*)(Wbf + off) = src[s];
        }
    }
    __syncthreads();

    int wv_ = tid >> 6, l = tid & 63;
    int wr = wv_ >> 1, wc = wv_ & 1;

    f32x4 acc[4][4];
#pragma unroll
    for (int i = 0; i < 4; ++i)
#pragma unroll
        for (int j = 0; j < 4; ++j) acc[i][j] = (f32x4){0.f, 0.f, 0.f, 0.f};

#pragma unroll
    for (int kc = 0; kc < 2; ++kc) {
        bf16x8 af[4], bfr[4];
#pragma unroll
        for (int pb = 0; pb < 4; ++pb) {
            int p = wr * 64 + pb * 16 + (l & 15);
            int off = (p * 128 + kc * 64 + (l >> 4) * 16) ^ ((p & 7) << 4);
            af[pb] = *(const bf16x8*)(Abf + off);
        }
#pragma unroll
        for (int cb = 0; cb < 4; ++cb) {
            int c = wc * 64 + cb * 16 + (l & 15);
            int off = (c * 128 + kc * 64 + (l >> 4) * 16) ^ ((c & 7) << 4);
            bfr[cb] = *(const bf16x8*)(Wbf + off);
        }
#pragma unroll
        for (int pb = 0; pb < 4; ++pb)
#pragma unroll
            for (int cb = 0; cb < 4; ++cb)
                acc[pb][cb] = __builtin_amdgcn_mfma_f32_16x16x32_bf16(
                    af[pb], bfr[cb], acc[pb][cb], 0, 0, 0);
    }
    __syncthreads();   // Abf/Wbf reads complete; lbuf becomes the out-tile

    // epilogue stage 1: u16 bf16 writes into [128 p][128 ch] tile
    float bias_c[4];
#pragma unroll
    for (int cb = 0; cb < 4; ++cb) bias_c[cb] = bias[wc * 64 + cb * 16 + (l & 15)];

#pragma unroll
    for (int pb = 0; pb < 4; ++pb) {
#pragma unroll
        for (int cb = 0; cb < 4; ++cb) {
            int c = wc * 64 + cb * 16 + (l & 15);
#pragma unroll
            for (int q = 0; q < 4; ++q) {
                int prow = wr * 64 + pb * 16 + (l >> 4) * 4 + q;
                float v = acc[pb][cb][q] + bias_c[cb];
                int byteoff = (prow * 256 + c * 2) ^ (((prow >> 2) & 3) << 5);
                *(unsigned short*)(lbuf + byteoff) = (unsigned short)bf16_rne(v);
            }
        }
    }
    __syncthreads();

    // epilogue stage 2: 16 lanes x uint4 = full 256B row per point
#pragma unroll
    for (int j = 0; j < 8; ++j) {
        int s = j * 256 + tid;
        int prow = s >> 4, chunk = s & 15;
        int byteoff = (prow * 256 + chunk * 16) ^ (((prow >> 2) & 3) << 5);
        uint4 val = *(const uint4*)(lbuf + byteoff);
        int pos = psl[prow];
        *((uint4*)(bevf + (size_t)pos * 64) + chunk) = val;
    }
}

// ---------------- pass 5: streaming register reduction -> float4 BCHW writeout ----------------
// Tile swizzle s(d,w) = (d + w + (w>>2)) & 63: accumulate-write 2-way, float4-read 2-way.
__global__ __launch_bounds__(512) void reduce_kernel(
        const unsigned* __restrict__ bevf, const int* __restrict__ cellstart,
        float* __restrict__ out) {
    __shared__ unsigned tile[256 * 64];   // 64 KiB
    int t = threadIdx.x;
    int blk = blockIdx.x;
    blk = (blk & 7) * (NSEG / 8) + (blk >> 3);   // XCD-contiguous segments
    int seg = blk;
    int wv = t >> 6, l = t & 63;

    int cell0 = seg * WWD + wv * 32;
    int idx = cell0 + l - 1;
    int bound = 0;
    if (l <= 32) bound = (idx < 0) ? 0 : cellstart[idx];   // lane i: orig[cell0+i]
    int r0 = __shfl(bound, 0);
    int r1 = __shfl(bound, 32);

    int j = 0;
    int ce = __shfl(bound, 1);
    float f0 = 0.f, f1 = 0.f;
    for (int r = r0; r < r1; r += 4) {
        unsigned v[4];
#pragma unroll
        for (int u = 0; u < 4; ++u) {
            int rr = (r + u < r1) ? r + u : r1 - 1;
            v[u] = bevf[(size_t)(rr + 1) * 64 + l];    // dense 256B/wave stream
        }
#pragma unroll
        for (int u = 0; u < 4; ++u) {
            if (r + u >= r1) break;
            while (r + u >= ce) {                      // wave-uniform cell advance
                int w = wv * 32 + j;
                tile[w * 64 + ((l + w + (w >> 2)) & 63)] = pack2(f0, f1);
                f0 = 0.f; f1 = 0.f;
                ++j;
                ce = __shfl(bound, j + 1);
            }
            f0 += __uint_as_float(v[u] << 16);
            f1 += __uint_as_float(v[u] & 0xFFFF0000u);
        }
    }
    while (j < 32) {                                   // flush tail (+empty cells)
        int w = wv * 32 + j;
        tile[w * 64 + ((l + w + (w >> 2)) & 63)] = pack2(f0, f1);
        f0 = 0.f; f1 = 0.f;
        ++j;
    }
    __syncthreads();

    int b = seg >> 8, h = seg & 255;
    float* ob = out + (size_t)b * OUTC * HWD + (size_t)h * WWD;
#pragma unroll
    for (int r = 0; r < 16; ++r) {
        int c = wv + 8 * r;
        int d = c >> 1;
        bool hi = c & 1;
        unsigned v0 = tile[(4 * l + 0) * 64 + ((d + 5 * l + 0) & 63)];
        unsigned v1 = tile[(4 * l + 1) * 64 + ((d + 5 * l + 1) & 63)];
        unsigned v2 = tile[(4 * l + 2) * 64 + ((d + 5 * l + 2) & 63)];
        unsigned v3 = tile[(4 * l + 3) * 64 + ((d + 5 * l + 3) & 63)];
        float4 o;
        o.x = __uint_as_float(hi ? (v0 & 0xFFFF0000u) : (v0 << 16));
        o.y = __uint_as_float(hi ? (v1 & 0xFFFF0000u) : (v1 << 16));
        o.z = __uint_as_float(hi ? (v2 & 0xFFFF0000u) : (v2 << 16));
        o.w = __uint_as_float(hi ? (v3 & 0xFFFF0000u) : (v3 << 16));
        *(float4*)(ob + (size_t)c * HWD + 4 * l) = o;   // 1KB per wave-instr
    }
}

// ---------------- fallback (ws too small): direct scattered atomics into BCHW ----------------
__global__ __launch_bounds__(256) void naive_kernel(
        const float* __restrict__ features, const float* __restrict__ kw,
        const float* __restrict__ bias,
        const int* __restrict__ bidx, const int* __restrict__ d0,
        const int* __restrict__ d1, const int* __restrict__ zi,
        float* __restrict__ out, int n) {
    long long gid = (long long)blockIdx.x * blockDim.x + threadIdx.x;
    int pid = (int)(gid >> 7);
    int c   = (int)(gid & (OUTC - 1));
    if (pid >= n) return;
    int z = zi[pid]; z = z < 0 ? 0 : (z > NZ - 1 ? NZ - 1 : z);
    const float4* fp = (const float4*)(features + (size_t)pid * INC);
    const float* wp = kw + (size_t)z * INC * OUTC + c;
    float a0 = bias[c], a1 = 0.f, a2 = 0.f, a3 = 0.f;
#pragma unroll
    for (int i = 0; i < INC / 4; ++i) {
        float4 f = fp[i];
        a0 += f.x * wp[(size_t)(4 * i + 0) * OUTC];
        a1 += f.y * wp[(size_t)(4 * i + 1) * OUTC];
        a2 += f.z * wp[(size_t)(4 * i + 2) * OUTC];
        a3 += f.w * wp[(size_t)(4 * i + 3) * OUTC];
    }
    float acc = (a0 + a1) + (a2 + a3);
    size_t oidx = ((size_t)bidx[pid] * OUTC + c) * HWD + (size_t)d0[pid] * WWD + d1[pid];
    unsafeAtomicAdd(&out[oidx], acc);
}

extern "C" void kernel_launch(void* const* d_in, const int* in_sizes, int n_in,
                              void* d_out, int out_size, void* d_ws, size_t ws_size,
                              hipStream_t stream) {
    const float* features = (const float*)d_in[0];
    const float* kw       = (const float*)d_in[1];
    const float* bias     = (const float*)d_in[2];
    const int* batch_idx  = (const int*)d_in[3];
    const int* d0_idx     = (const int*)d_in[4];
    const int* d1_idx     = (const int*)d_in[5];
    const int* z_idx      = (const int*)d_in[6];
    float* out = (float*)d_out;
    int n = in_sizes[0] / INC;   // number of points

    size_t binsElems = (size_t)n + (size_t)NZ * PPB;
    size_t bevfBytes = (binsElems + 1) * OUTC * 2;           // ~77.5 MB
    size_t wtOff     = (bevfBytes + 255) & ~(size_t)255;     // bf16 Wt: 128 KiB
    size_t metaOff   = wtOff + (size_t)NZ * OUTC * INC * 2;
    size_t chOff     = (metaOff + 32 * 4 + 255) & ~(size_t)255;   // cellhist
    size_t csOff     = chOff + (size_t)NCELL * 4;            // cellstart (NCELL+4)
    size_t ckOff     = csOff + (size_t)(NCELL + 4) * 4;      // chunksum (256)
    size_t binsOff   = (ckOff + 256 * 4 + 255) & ~(size_t)255;
    size_t posOff    = binsOff + binsElems * 4;
    size_t need      = posOff + binsElems * 4 + 16;

    if (ws_size >= need) {
        char* ws = (char*)d_ws;
        unsigned* bevf = (unsigned*)ws;
        unsigned short* wt = (unsigned short*)(ws + wtOff);
        int* meta      = (int*)(ws + metaOff);   // counts[8], cursors[8], pstart[9]
        int* counts    = meta;
        int* cursors   = meta + 8;
        int* pstart    = meta + 16;
        int* cellhist  = (int*)(ws + chOff);
        int* cellstart = (int*)(ws + csOff);
        int* chunksum  = (int*)(ws + ckOff);
        int* bins      = (int*)(ws + binsOff);
        int* segpos    = (int*)(ws + posOff);

        hipMemsetAsync(meta, 0, 32 * 4, stream);
        hipMemsetAsync(cellhist, 0, (size_t)NCELL * 4, stream);

        int gb = (n + 255) / 256;
        wprep_kernel<<<NZ, 256, 0, stream>>>(kw, wt);
        hist_kernel<<<gb, 256, 0, stream>>>(z_idx, batch_idx, d0_idx, d1_idx,
                                            counts, cellhist, n);
        scan_local<<<256, 256, 0, stream>>>(cellhist, cellstart, chunksum,
                                            counts, pstart);
        scan_add2<<<256, 256, 0, stream>>>(cellstart, chunksum);
        scatter_kernel<<<gb, 256, 0, stream>>>(z_idx, batch_idx, d0_idx, d1_idx,
                                               pstart, cursors, cellstart,
                                               bins, segpos, n);

        int nblk = (int)((binsElems + PPB - 1) / PPB) + 1;
        gemm_kernel<<<nblk, 256, 0, stream>>>(features, wt, bias, counts, pstart,
                                              bins, segpos, bevf);

        reduce_kernel<<<NSEG, 512, 0, stream>>>(bevf, cellstart, out);
    } else {
        hipMemsetAsync(out, 0, (size_t)out_size * sizeof(float), stream);
        long long threads = (long long)n * OUTC;
        int gb = (int)((threads + 255) / 256);
        naive_kernel<<<gb, 256, 0, stream>>>(features, kw, bias, batch_idx, d0_idx,
                                             d1_idx, z_idx, out, n);
    }
}

// Round 14
// 146.684 us; speedup vs baseline: 1.4849x; 1.0393x over previous
//
#include <hip/hip_runtime.h>

#define PPB   128
#define NZ    8
#define INC   64
#define OUTC  128
#define NB    4
#define HH    256
#define WWD   256
#define HWD   (HH * WWD)
#define NSEG  (NB * HH)          // 1024 row segments (b*HH + h)
#define NCELL (NB * HH * WWD)    // 262144 cells (flat bev index)

typedef __attribute__((ext_vector_type(8))) short bf16x8;
typedef __attribute__((ext_vector_type(4))) float f32x4;

__device__ __forceinline__ unsigned bf16_rne(float x) {
    unsigned u = __float_as_uint(x);
    return (u + 0x7FFFu + ((u >> 16) & 1u)) >> 16;
}
__device__ __forceinline__ unsigned pack2(float lo, float hi) {
    return bf16_rne(lo) | (bf16_rne(hi) << 16);
}

// ---------------- pass 0: W transpose to bf16 [z][c][k] + zero meta/cellhist ----------------
__global__ __launch_bounds__(256) void wprep_kernel(const float* __restrict__ kw,
                                                    unsigned short* __restrict__ wt,
                                                    int* __restrict__ meta,
                                                    int* __restrict__ cellhist) {
    int z = blockIdx.x;   // 0..7
    int t = threadIdx.x;
    if (z == 0 && t < 32) meta[t] = 0;
    {   // zero cellhist: 2048 threads x 32 int4 = 65536 int4 = NCELL ints
        int4 zero4 = make_int4(0, 0, 0, 0);
        int4* ch4 = (int4*)cellhist;
        int idx0 = (z * 256 + t) * 32;
#pragma unroll
        for (int i = 0; i < 32; ++i) ch4[idx0 + i] = zero4;
    }
    const float* src = kw + (size_t)z * INC * OUTC;    // [k][c] fp32
    unsigned short* dst = wt + (size_t)z * OUTC * INC; // [c][k] bf16
    for (int c = t; c < OUTC; c += 256) {
#pragma unroll
        for (int k = 0; k < INC; k += 2) {
            float a = src[(size_t)k * OUTC + c];
            float b = src[(size_t)(k + 1) * OUTC + c];
            *(unsigned*)&dst[(size_t)c * INC + k] = pack2(a, b);
        }
    }
}

// ---------------- pass 1: z histogram + cell histogram ----------------
__global__ void hist_kernel(const int* __restrict__ z_idx, const int* __restrict__ batch_idx,
                            const int* __restrict__ d0_idx, const int* __restrict__ d1_idx,
                            int* __restrict__ counts, int* __restrict__ cellhist, int n) {
    __shared__ int lc[NZ];
    int t = threadIdx.x;
    if (t < NZ) lc[t] = 0;
    __syncthreads();
    int i = blockIdx.x * blockDim.x + t;
    if (i < n) {
        int z = z_idx[i]; z = z < 0 ? 0 : (z > NZ - 1 ? NZ - 1 : z);
        atomicAdd(&lc[z], 1);
        int cell = (batch_idx[i] * HH + d0_idx[i]) * WWD + d1_idx[i];
        atomicAdd(&cellhist[cell], 1);
    }
    __syncthreads();
    if (t < NZ && lc[t] > 0) atomicAdd(&counts[t], lc[t]);
}

// ---------------- pass 2a: local exclusive scan per 1024-chunk (+z padded prefix) ----------------
__global__ __launch_bounds__(256) void scan_local(const int* __restrict__ cellhist,
                                                  int* __restrict__ cellstart,
                                                  int* __restrict__ chunksum,
                                                  const int* __restrict__ counts,
                                                  int* __restrict__ pstart) {
    if (blockIdx.x == 0 && threadIdx.x == 0) {   // folded z-bin padded prefix
        int off = 0;
        for (int z = 0; z < NZ; ++z) {
            pstart[z] = off;
            off += ((counts[z] + PPB - 1) / PPB) * PPB;
        }
        pstart[NZ] = off;
    }
    __shared__ int ts[256];
    int t = threadIdx.x;
    int base = blockIdx.x * 1024 + t * 4;
    int4 v = *(const int4*)&cellhist[base];
    int s = v.x + v.y + v.z + v.w;
    ts[t] = s;
    __syncthreads();
    for (int d = 1; d < 256; d <<= 1) {
        int x = (t >= d) ? ts[t - d] : 0;
        __syncthreads();
        ts[t] += x;
        __syncthreads();
    }
    int excl = ts[t] - s;
    int4 o;
    o.x = excl; o.y = excl + v.x; o.z = o.y + v.y; o.w = o.z + v.z;
    *(int4*)&cellstart[base] = o;
    if (t == 255) chunksum[blockIdx.x] = ts[255];
}

// ---------------- pass 2b: each block sums prior chunksums itself and adds ----------------
__global__ __launch_bounds__(256) void scan_add2(int* __restrict__ cellstart,
                                                 const int* __restrict__ chunksum) {
    __shared__ int ts[256];
    int t = threadIdx.x;
    int b = blockIdx.x;
    ts[t] = (t < b) ? chunksum[t] : 0;
    __syncthreads();
    for (int d = 128; d > 0; d >>= 1) {
        if (t < d) ts[t] += ts[t + d];
        __syncthreads();
    }
    int off = ts[0];
    if (off == 0) return;
    int base = b * 1024 + t * 4;
    int4 v = *(int4*)&cellstart[base];
    v.x += off; v.y += off; v.z += off; v.w += off;
    *(int4*)&cellstart[base] = v;
}

// ---------------- pass 3: scatter ids into z bins + cell-sorted positions ----------------
// Mutates cellstart in place: after completion, cellstart[c] == orig[c+1].
__global__ void scatter_kernel(const int* __restrict__ z_idx, const int* __restrict__ batch_idx,
                               const int* __restrict__ d0_idx, const int* __restrict__ d1_idx,
                               const int* __restrict__ pstart, int* __restrict__ cursors,
                               int* __restrict__ cellstart,
                               int* __restrict__ bins, int* __restrict__ segpos, int n) {
    __shared__ int lc[NZ];
    __shared__ int lbase[NZ];
    int t = threadIdx.x;
    if (t < NZ) lc[t] = 0;
    __syncthreads();
    int i = blockIdx.x * blockDim.x + t;
    int z = 0, rank = 0;
    bool valid = (i < n);
    if (valid) {
        z = z_idx[i]; z = z < 0 ? 0 : (z > NZ - 1 ? NZ - 1 : z);
        rank = atomicAdd(&lc[z], 1);
    }
    __syncthreads();
    if (t < NZ) lbase[t] = (lc[t] > 0) ? atomicAdd(&cursors[t], lc[t]) : 0;
    __syncthreads();
    if (valid) {
        int slot = pstart[z] + lbase[z] + rank;
        bins[slot] = i;
        int cell = (batch_idx[i] * HH + d0_idx[i]) * WWD + d1_idx[i];
        int r2 = atomicAdd(&cellstart[cell], 1);   // returns cell-sorted position
        segpos[slot] = 1 + r2;                     // row 0 of bevf = dump
    }
}

// ---------------- pass 4: bf16 MFMA GEMM per z-bin -> bf16 rows at cell-sorted pos ----------------
__global__ __launch_bounds__(256) void gemm_kernel(
        const float* __restrict__ features, const unsigned short* __restrict__ wt,
        const float* __restrict__ bias, const int* __restrict__ counts,
        const int* __restrict__ pstart, const int* __restrict__ bins,
        const int* __restrict__ segpos, unsigned* __restrict__ bevf) {
    __shared__ __align__(16) char lbuf[32768];   // Abf+Wbf, then out-tile
    __shared__ int psl[PPB];
    char* Abf = lbuf;              // [128 p][64 k] bf16, swizzled
    char* Wbf = lbuf + 16384;      // [128 c][64 k] bf16, swizzled

    int start = blockIdx.x * PPB;
    int total = pstart[NZ];
    if (start >= total) return;
    int z = 0;
#pragma unroll
    for (int zz = 1; zz < NZ; ++zz)
        if (start >= pstart[zz]) z = zz;
    int limit = pstart[z] + counts[z] - start;   // slots [0,limit) are real points
    if (limit <= 0) return;                      // fully-padded block

    int tid = threadIdx.x;
    if (tid < PPB) psl[tid] = (tid < limit) ? segpos[start + tid] : 0;   // pad -> dump

    {   // stage A: gather feature rows -> bf16 k-contig, swizzled b128 writes
        int r = tid >> 1, half = tid & 1;
        int raw = (r < limit) ? bins[start + r] : 0;
        int nid = raw < 0 ? 0 : raw;
        const float4* fp = (const float4*)(features + (size_t)nid * INC) + half * 8;
        float4 f[8];
#pragma unroll
        for (int q = 0; q < 8; ++q) f[q] = fp[q];
        unsigned u[16];
#pragma unroll
        for (int m = 0; m < 8; ++m) {
            u[2 * m]     = pack2(f[m].x, f[m].y);
            u[2 * m + 1] = pack2(f[m].z, f[m].w);
        }
#pragma unroll
        for (int ch = 0; ch < 4; ++ch) {
            int off = (r * 128 + half * 64 + ch * 16) ^ ((r & 7) << 4);
            uint4 val = make_uint4(u[4 * ch], u[4 * ch + 1], u[4 * ch + 2], u[4 * ch + 3]);
            *(uint4*)(Abf + off) = val;
        }
    }
    {   // stage W: coalesced 16KB copy of pre-transposed bf16 Wt[z] ([c][k])
        const uint4* src = (const uint4*)(wt + (size_t)z * OUTC * INC);
#pragma unroll
        for (int i = 0; i < 4; ++i) {
            int s = tid + 256 * i;
            int c = s >> 3, ch = s & 7;
            int off = (c * 128 + ch * 16) ^ ((c & 7) << 4);
            *(uint4*)(Wbf + off) = src[s];
        }
    }
    __syncthreads();

    int wv_ = tid >> 6, l = tid & 63;
    int wr = wv_ >> 1, wc = wv_ & 1;

    f32x4 acc[4][4];
#pragma unroll
    for (int i = 0; i < 4; ++i)
#pragma unroll
        for (int j = 0; j < 4; ++j) acc[i][j] = (f32x4){0.f, 0.f, 0.f, 0.f};

#pragma unroll
    for (int kc = 0; kc < 2; ++kc) {
        bf16x8 af[4], bfr[4];
#pragma unroll
        for (int pb = 0; pb < 4; ++pb) {
            int p = wr * 64 + pb * 16 + (l & 15);
            int off = (p * 128 + kc * 64 + (l >> 4) * 16) ^ ((p & 7) << 4);
            af[pb] = *(const bf16x8*)(Abf + off);
        }
#pragma unroll
        for (int cb = 0; cb < 4; ++cb) {
            int c = wc * 64 + cb * 16 + (l & 15);
            int off = (c * 128 + kc * 64 + (l >> 4) * 16) ^ ((c & 7) << 4);
            bfr[cb] = *(const bf16x8*)(Wbf + off);
        }
#pragma unroll
        for (int pb = 0; pb < 4; ++pb)
#pragma unroll
            for (int cb = 0; cb < 4; ++cb)
                acc[pb][cb] = __builtin_amdgcn_mfma_f32_16x16x32_bf16(
                    af[pb], bfr[cb], acc[pb][cb], 0, 0, 0);
    }
    __syncthreads();   // Abf/Wbf reads complete; lbuf becomes the out-tile

    // epilogue stage 1: u16 bf16 writes into [128 p][128 ch] tile
    float bias_c[4];
#pragma unroll
    for (int cb = 0; cb < 4; ++cb) bias_c[cb] = bias[wc * 64 + cb * 16 + (l & 15)];

#pragma unroll
    for (int pb = 0; pb < 4; ++pb) {
#pragma unroll
        for (int cb = 0; cb < 4; ++cb) {
            int c = wc * 64 + cb * 16 + (l & 15);
#pragma unroll
            for (int q = 0; q < 4; ++q) {
                int prow = wr * 64 + pb * 16 + (l >> 4) * 4 + q;
                float v = acc[pb][cb][q] + bias_c[cb];
                int byteoff = (prow * 256 + c * 2) ^ (((prow >> 2) & 3) << 5);
                *(unsigned short*)(lbuf + byteoff) = (unsigned short)bf16_rne(v);
            }
        }
    }
    __syncthreads();

    // epilogue stage 2: 16 lanes x uint4 = full 256B row per point
#pragma unroll
    for (int j = 0; j < 8; ++j) {
        int s = j * 256 + tid;
        int prow = s >> 4, chunk = s & 15;
        int byteoff = (prow * 256 + chunk * 16) ^ (((prow >> 2) & 3) << 5);
        uint4 val = *(const uint4*)(lbuf + byteoff);
        int pos = psl[prow];
        *((uint4*)(bevf + (size_t)pos * 64) + chunk) = val;
    }
}

// ---------------- pass 5: quarter-wave uint4 streaming reduction -> float4 BCHW writeout ----------------
// Quarter-wave qw (16 lanes) owns 8 cells; lane m holds dwords 4m..4m+3 (8 fp32 accs).
// One row load = uint4/lane = 1KB per wave-instruction; boundaries via __shfl(..,16).
// Tile swizzle s(d,w) = (d + w + (w>>2)) & 63 (write 2-way, float4-read 2-way).
__global__ __launch_bounds__(512) void reduce_kernel(
        const unsigned* __restrict__ bevf, const int* __restrict__ cellstart,
        float* __restrict__ out) {
    __shared__ unsigned tile[256 * 64];   // 64 KiB
    int t = threadIdx.x;
    int blk = blockIdx.x;
    blk = (blk & 7) * (NSEG / 8) + (blk >> 3);   // XCD-contiguous segments
    int seg = blk;

    int qw = t >> 4;          // quarter-wave 0..31
    int m  = t & 15;          // lane within quarter-wave
    int w0 = qw * 8;          // first cell (w index) of this quarter-wave
    int cell0 = seg * WWD + w0;

    int idx = cell0 + m - 1;
    int bound = 0;
    if (m <= 8) bound = (idx < 0) ? 0 : cellstart[idx];   // lane m: orig[cell0+m]
    int r0 = __shfl(bound, 0, 16);
    int r1 = __shfl(bound, 8, 16);

    float f[8];
#pragma unroll
    for (int i = 0; i < 8; ++i) f[i] = 0.f;
    int j = 0;
    int ce = __shfl(bound, 1, 16);

    for (int r = r0; r < r1; r += 4) {
        uint4 v[4];
#pragma unroll
        for (int u = 0; u < 4; ++u) {
            int rr = (r + u < r1) ? r + u : r1 - 1;
            v[u] = *(const uint4*)&bevf[(size_t)(rr + 1) * 64 + 4 * m];  // 1KB/wave stream
        }
#pragma unroll
        for (int u = 0; u < 4; ++u) {
            if (r + u >= r1) break;
            while (r + u >= ce) {                     // quarter-wave-uniform cell advance
                int w = w0 + j;
                int sb = w + (w >> 2);
                tile[w * 64 + ((4 * m + 0 + sb) & 63)] = pack2(f[0], f[1]);
                tile[w * 64 + ((4 * m + 1 + sb) & 63)] = pack2(f[2], f[3]);
                tile[w * 64 + ((4 * m + 2 + sb) & 63)] = pack2(f[4], f[5]);
                tile[w * 64 + ((4 * m + 3 + sb) & 63)] = pack2(f[6], f[7]);
#pragma unroll
                for (int i = 0; i < 8; ++i) f[i] = 0.f;
                ++j;
                ce = __shfl(bound, j + 1, 16);
            }
            f[0] += __uint_as_float(v[u].x << 16);
            f[1] += __uint_as_float(v[u].x & 0xFFFF0000u);
            f[2] += __uint_as_float(v[u].y << 16);
            f[3] += __uint_as_float(v[u].y & 0xFFFF0000u);
            f[4] += __uint_as_float(v[u].z << 16);
            f[5] += __uint_as_float(v[u].z & 0xFFFF0000u);
            f[6] += __uint_as_float(v[u].w << 16);
            f[7] += __uint_as_float(v[u].w & 0xFFFF0000u);
        }
    }
    while (j < 8) {                                   // flush tail (+empty cells)
        int w = w0 + j;
        int sb = w + (w >> 2);
        tile[w * 64 + ((4 * m + 0 + sb) & 63)] = pack2(f[0], f[1]);
        tile[w * 64 + ((4 * m + 1 + sb) & 63)] = pack2(f[2], f[3]);
        tile[w * 64 + ((4 * m + 2 + sb) & 63)] = pack2(f[4], f[5]);
        tile[w * 64 + ((4 * m + 3 + sb) & 63)] = pack2(f[6], f[7]);
#pragma unroll
        for (int i = 0; i < 8; ++i) f[i] = 0.f;
        ++j;
    }
    __syncthreads();

    int wv = t >> 6, l = t & 63;
    int b = seg >> 8, h = seg & 255;
    float* ob = out + (size_t)b * OUTC * HWD + (size_t)h * WWD;
#pragma unroll
    for (int r = 0; r < 16; ++r) {
        int c = wv + 8 * r;
        int d = c >> 1;
        bool hi = c & 1;
        unsigned v0 = tile[(4 * l + 0) * 64 + ((d + 5 * l + 0) & 63)];
        unsigned v1 = tile[(4 * l + 1) * 64 + ((d + 5 * l + 1) & 63)];
        unsigned v2 = tile[(4 * l + 2) * 64 + ((d + 5 * l + 2) & 63)];
        unsigned v3 = tile[(4 * l + 3) * 64 + ((d + 5 * l + 3) & 63)];
        float4 o;
        o.x = __uint_as_float(hi ? (v0 & 0xFFFF0000u) : (v0 << 16));
        o.y = __uint_as_float(hi ? (v1 & 0xFFFF0000u) : (v1 << 16));
        o.z = __uint_as_float(hi ? (v2 & 0xFFFF0000u) : (v2 << 16));
        o.w = __uint_as_float(hi ? (v3 & 0xFFFF0000u) : (v3 << 16));
        *(float4*)(ob + (size_t)c * HWD + 4 * l) = o;   // 1KB per wave-instr
    }
}

// ---------------- fallback (ws too small): direct scattered atomics into BCHW ----------------
__global__ __launch_bounds__(256) void naive_kernel(
        const float* __restrict__ features, const float* __restrict__ kw,
        const float* __restrict__ bias,
        const int* __restrict__ bidx, const int* __restrict__ d0,
        const int* __restrict__ d1, const int* __restrict__ zi,
        float* __restrict__ out, int n) {
    long long gid = (long long)blockIdx.x * blockDim.x + threadIdx.x;
    int pid = (int)(gid >> 7);
    int c   = (int)(gid & (OUTC - 1));
    if (pid >= n) return;
    int z = zi[pid]; z = z < 0 ? 0 : (z > NZ - 1 ? NZ - 1 : z);
    const float4* fp = (const float4*)(features + (size_t)pid * INC);
    const float* wp = kw + (size_t)z * INC * OUTC + c;
    float a0 = bias[c], a1 = 0.f, a2 = 0.f, a3 = 0.f;
#pragma unroll
    for (int i = 0; i < INC / 4; ++i) {
        float4 f = fp[i];
        a0 += f.x * wp[(size_t)(4 * i + 0) * OUTC];
        a1 += f.y * wp[(size_t)(4 * i + 1) * OUTC];
        a2 += f.z * wp[(size_t)(4 * i + 2) * OUTC];
        a3 += f.w * wp[(size_t)(4 * i + 3) * OUTC];
    }
    float acc = (a0 + a1) + (a2 + a3);
    size_t oidx = ((size_t)bidx[pid] * OUTC + c) * HWD + (size_t)d0[pid] * WWD + d1[pid];
    unsafeAtomicAdd(&out[oidx], acc);
}

extern "C" void kernel_launch(void* const* d_in, const int* in_sizes, int n_in,
                              void* d_out, int out_size, void* d_ws, size_t ws_size,
                              hipStream_t stream) {
    const float* features = (const float*)d_in[0];
    const float* kw       = (const float*)d_in[1];
    const float* bias     = (const float*)d_in[2];
    const int* batch_idx  = (const int*)d_in[3];
    const int* d0_idx     = (const int*)d_in[4];
    const int* d1_idx     = (const int*)d_in[5];
    const int* z_idx      = (const int*)d_in[6];
    float* out = (float*)d_out;
    int n = in_sizes[0] / INC;   // number of points

    size_t binsElems = (size_t)n + (size_t)NZ * PPB;
    size_t bevfBytes = (binsElems + 1) * OUTC * 2;           // ~77.5 MB
    size_t wtOff     = (bevfBytes + 255) & ~(size_t)255;     // bf16 Wt: 128 KiB
    size_t metaOff   = wtOff + (size_t)NZ * OUTC * INC * 2;
    size_t chOff     = (metaOff + 32 * 4 + 255) & ~(size_t)255;   // cellhist
    size_t csOff     = chOff + (size_t)NCELL * 4;            // cellstart (NCELL+4)
    size_t ckOff     = csOff + (size_t)(NCELL + 4) * 4;      // chunksum (256)
    size_t binsOff   = (ckOff + 256 * 4 + 255) & ~(size_t)255;
    size_t posOff    = binsOff + binsElems * 4;
    size_t need      = posOff + binsElems * 4 + 16;

    if (ws_size >= need) {
        char* ws = (char*)d_ws;
        unsigned* bevf = (unsigned*)ws;
        unsigned short* wt = (unsigned short*)(ws + wtOff);
        int* meta      = (int*)(ws + metaOff);   // counts[8], cursors[8], pstart[9]
        int* counts    = meta;
        int* cursors   = meta + 8;
        int* pstart    = meta + 16;
        int* cellhist  = (int*)(ws + chOff);
        int* cellstart = (int*)(ws + csOff);
        int* chunksum  = (int*)(ws + ckOff);
        int* bins      = (int*)(ws + binsOff);
        int* segpos    = (int*)(ws + posOff);

        int gb = (n + 255) / 256;
        wprep_kernel<<<NZ, 256, 0, stream>>>(kw, wt, meta, cellhist);
        hist_kernel<<<gb, 256, 0, stream>>>(z_idx, batch_idx, d0_idx, d1_idx,
                                            counts, cellhist, n);
        scan_local<<<256, 256, 0, stream>>>(cellhist, cellstart, chunksum,
                                            counts, pstart);
        scan_add2<<<256, 256, 0, stream>>>(cellstart, chunksum);
        scatter_kernel<<<gb, 256, 0, stream>>>(z_idx, batch_idx, d0_idx, d1_idx,
                                               pstart, cursors, cellstart,
                                               bins, segpos, n);

        int nblk = (int)((binsElems + PPB - 1) / PPB) + 1;
        gemm_kernel<<<nblk, 256, 0, stream>>>(features, wt, bias, counts, pstart,
                                              bins, segpos, bevf);

        reduce_kernel<<<NSEG, 512, 0, stream>>>(bevf, cellstart, out);
    } else {
        hipMemsetAsync(out, 0, (size_t)out_size * sizeof(float), stream);
        long long threads = (long long)n * OUTC;
        int gb = (int)((threads + 255) / 256);
        naive_kernel<<<gb, 256, 0, stream>>>(features, kw, bias, batch_idx, d0_idx,
                                             d1_idx, z_idx, out, n);
    }
}

// Round 15
// 144.721 us; speedup vs baseline: 1.5050x; 1.0136x over previous
//
#include <hip/hip_runtime.h>

#define PPB   128
#define NZ    8
#define INC   64
#define OUTC  128
#define NB    4
#define HH    256
#define WWD   256
#define HWD   (HH * WWD)
#define NSEG  (NB * HH)          // 1024 row segments (b*HH + h)
#define NCELL (NB * HH * WWD)    // 262144 cells (flat bev index)

typedef __attribute__((ext_vector_type(8))) short bf16x8;
typedef __attribute__((ext_vector_type(4))) float f32x4;

__device__ __forceinline__ unsigned bf16_rne(float x) {
    unsigned u = __float_as_uint(x);
    return (u + 0x7FFFu + ((u >> 16) & 1u)) >> 16;
}
__device__ __forceinline__ unsigned pack2(float lo, float hi) {
    return bf16_rne(lo) | (bf16_rne(hi) << 16);
}

// ---------------- pass 0: W transpose to bf16 [z][c][k] + zero meta/cellhist ----------------
__global__ __launch_bounds__(256) void wprep_kernel(const float* __restrict__ kw,
                                                    unsigned short* __restrict__ wt,
                                                    int* __restrict__ meta,
                                                    int* __restrict__ cellhist) {
    int z = blockIdx.x;   // 0..7
    int t = threadIdx.x;
    if (z == 0 && t < 32) meta[t] = 0;
    {   // zero cellhist: 2048 threads x 32 int4 = NCELL ints
        int4 zero4 = make_int4(0, 0, 0, 0);
        int4* ch4 = (int4*)cellhist;
        int idx0 = (z * 256 + t) * 32;
#pragma unroll
        for (int i = 0; i < 32; ++i) ch4[idx0 + i] = zero4;
    }
    const float* src = kw + (size_t)z * INC * OUTC;    // [k][c] fp32
    unsigned short* dst = wt + (size_t)z * OUTC * INC; // [c][k] bf16
    for (int c = t; c < OUTC; c += 256) {
#pragma unroll
        for (int k = 0; k < INC; k += 2) {
            float a = src[(size_t)k * OUTC + c];
            float b = src[(size_t)(k + 1) * OUTC + c];
            *(unsigned*)&dst[(size_t)c * INC + k] = pack2(a, b);
        }
    }
}

// ---------------- pass 1: z histogram + cell histogram ----------------
__global__ void hist_kernel(const int* __restrict__ z_idx, const int* __restrict__ batch_idx,
                            const int* __restrict__ d0_idx, const int* __restrict__ d1_idx,
                            int* __restrict__ counts, int* __restrict__ cellhist, int n) {
    __shared__ int lc[NZ];
    int t = threadIdx.x;
    if (t < NZ) lc[t] = 0;
    __syncthreads();
    int i = blockIdx.x * blockDim.x + t;
    if (i < n) {
        int z = z_idx[i]; z = z < 0 ? 0 : (z > NZ - 1 ? NZ - 1 : z);
        atomicAdd(&lc[z], 1);
        int cell = (batch_idx[i] * HH + d0_idx[i]) * WWD + d1_idx[i];
        atomicAdd(&cellhist[cell], 1);
    }
    __syncthreads();
    if (t < NZ && lc[t] > 0) atomicAdd(&counts[t], lc[t]);
}

// ---------------- pass 2: local exclusive scan per 1024-chunk (+z padded prefix) ----------------
// cellstart stays CHUNK-LOCAL; chunksum[b] = chunk total. Consumers add cko on the fly.
__global__ __launch_bounds__(256) void scan_local(const int* __restrict__ cellhist,
                                                  int* __restrict__ cellstart,
                                                  int* __restrict__ chunksum,
                                                  const int* __restrict__ counts,
                                                  int* __restrict__ pstart) {
    if (blockIdx.x == 0 && threadIdx.x == 0) {   // folded z-bin padded prefix
        int off = 0;
        for (int z = 0; z < NZ; ++z) {
            pstart[z] = off;
            off += ((counts[z] + PPB - 1) / PPB) * PPB;
        }
        pstart[NZ] = off;
    }
    __shared__ int ts[256];
    int t = threadIdx.x;
    int base = blockIdx.x * 1024 + t * 4;
    int4 v = *(const int4*)&cellhist[base];
    int s = v.x + v.y + v.z + v.w;
    ts[t] = s;
    __syncthreads();
    for (int d = 1; d < 256; d <<= 1) {
        int x = (t >= d) ? ts[t - d] : 0;
        __syncthreads();
        ts[t] += x;
        __syncthreads();
    }
    int excl = ts[t] - s;
    int4 o;
    o.x = excl; o.y = excl + v.x; o.z = o.y + v.y; o.w = o.z + v.z;
    *(int4*)&cellstart[base] = o;
    if (t == 255) chunksum[blockIdx.x] = ts[255];
}

// ---------------- pass 3: scatter ids into z bins + cell-sorted GLOBAL positions ----------------
// Per-block 256-int scan of chunksum -> cko; segpos = local pos + cko[cell>>10].
// Mutates cellstart in place (stays chunk-local): mut[c] = local_excl[c] + cnt[c].
__global__ __launch_bounds__(256) void scatter_kernel(
        const int* __restrict__ z_idx, const int* __restrict__ batch_idx,
        const int* __restrict__ d0_idx, const int* __restrict__ d1_idx,
        const int* __restrict__ pstart, int* __restrict__ cursors,
        int* __restrict__ cellstart, const int* __restrict__ chunksum,
        int* __restrict__ bins, int* __restrict__ segpos, int n) {
    __shared__ int lc[NZ];
    __shared__ int lbase[NZ];
    __shared__ int cko[256];
    int t = threadIdx.x;
    if (t < NZ) lc[t] = 0;
    {   // exclusive scan of chunksum into cko
        int s = chunksum[t];
        cko[t] = s;
        __syncthreads();
        for (int d = 1; d < 256; d <<= 1) {
            int x = (t >= d) ? cko[t - d] : 0;
            __syncthreads();
            cko[t] += x;
            __syncthreads();
        }
        int excl = cko[t] - s;
        __syncthreads();
        cko[t] = excl;
    }
    __syncthreads();
    int i = blockIdx.x * blockDim.x + t;
    int z = 0, rank = 0;
    bool valid = (i < n);
    if (valid) {
        z = z_idx[i]; z = z < 0 ? 0 : (z > NZ - 1 ? NZ - 1 : z);
        rank = atomicAdd(&lc[z], 1);
    }
    __syncthreads();
    if (t < NZ) lbase[t] = (lc[t] > 0) ? atomicAdd(&cursors[t], lc[t]) : 0;
    __syncthreads();
    if (valid) {
        int slot = pstart[z] + lbase[z] + rank;
        bins[slot] = i;
        int cell = (batch_idx[i] * HH + d0_idx[i]) * WWD + d1_idx[i];
        int r2 = atomicAdd(&cellstart[cell], 1);       // chunk-local position
        segpos[slot] = 1 + r2 + cko[cell >> 10];       // global; row 0 = dump
    }
}

// ---------------- pass 4: bf16 MFMA GEMM per z-bin -> bf16 rows at cell-sorted pos ----------------
// B-fragments register-resident from global wt (L2/L1-hot, z-uniform block) — no Wbf LDS.
__global__ __launch_bounds__(256) void gemm_kernel(
        const float* __restrict__ features, const unsigned short* __restrict__ wt,
        const float* __restrict__ bias, const int* __restrict__ counts,
        const int* __restrict__ pstart, const int* __restrict__ bins,
        const int* __restrict__ segpos, unsigned* __restrict__ bevf) {
    __shared__ __align__(16) char lbuf[32768];   // Abf (16KB), then 32KB out-tile
    __shared__ int psl[PPB];
    char* Abf = lbuf;              // [128 p][64 k] bf16, swizzled

    int start = blockIdx.x * PPB;
    int total = pstart[NZ];
    if (start >= total) return;
    int z = 0;
#pragma unroll
    for (int zz = 1; zz < NZ; ++zz)
        if (start >= pstart[zz]) z = zz;
    int limit = pstart[z] + counts[z] - start;   // slots [0,limit) are real points
    if (limit <= 0) return;                      // fully-padded block

    int tid = threadIdx.x;
    int wv_ = tid >> 6, l = tid & 63;
    int wr = wv_ >> 1, wc = wv_ & 1;

    if (tid < PPB) psl[tid] = (tid < limit) ? segpos[start + tid] : 0;   // pad -> dump

    // B-fragments: 8 x bf16x8 = 32 VGPR, direct from global (same addr across waves -> L1)
    bf16x8 bfr[4][2];
#pragma unroll
    for (int cb = 0; cb < 4; ++cb)
#pragma unroll
        for (int kc = 0; kc < 2; ++kc)
            bfr[cb][kc] = *(const bf16x8*)&wt[(size_t)z * OUTC * INC +
                (size_t)(wc * 64 + cb * 16 + (l & 15)) * INC + kc * 32 + (l >> 4) * 8];

    {   // stage A: gather feature rows -> bf16 k-contig, swizzled b128 writes
        int r = tid >> 1, half = tid & 1;
        int raw = (r < limit) ? bins[start + r] : 0;
        int nid = raw < 0 ? 0 : raw;
        const float4* fp = (const float4*)(features + (size_t)nid * INC) + half * 8;
        float4 f[8];
#pragma unroll
        for (int q = 0; q < 8; ++q) f[q] = fp[q];
        unsigned u[16];
#pragma unroll
        for (int m = 0; m < 8; ++m) {
            u[2 * m]     = pack2(f[m].x, f[m].y);
            u[2 * m + 1] = pack2(f[m].z, f[m].w);
        }
#pragma unroll
        for (int ch = 0; ch < 4; ++ch) {
            int off = (r * 128 + half * 64 + ch * 16) ^ ((r & 7) << 4);
            uint4 val = make_uint4(u[4 * ch], u[4 * ch + 1], u[4 * ch + 2], u[4 * ch + 3]);
            *(uint4*)(Abf + off) = val;
        }
    }
    __syncthreads();

    f32x4 acc[4][4];
#pragma unroll
    for (int i = 0; i < 4; ++i)
#pragma unroll
        for (int j = 0; j < 4; ++j) acc[i][j] = (f32x4){0.f, 0.f, 0.f, 0.f};

#pragma unroll
    for (int kc = 0; kc < 2; ++kc) {
        bf16x8 af[4];
#pragma unroll
        for (int pb = 0; pb < 4; ++pb) {
            int p = wr * 64 + pb * 16 + (l & 15);
            int off = (p * 128 + kc * 64 + (l >> 4) * 16) ^ ((p & 7) << 4);
            af[pb] = *(const bf16x8*)(Abf + off);
        }
#pragma unroll
        for (int pb = 0; pb < 4; ++pb)
#pragma unroll
            for (int cb = 0; cb < 4; ++cb)
                acc[pb][cb] = __builtin_amdgcn_mfma_f32_16x16x32_bf16(
                    af[pb], bfr[cb][kc], acc[pb][cb], 0, 0, 0);
    }
    __syncthreads();   // Abf reads complete; lbuf becomes the out-tile

    // epilogue stage 1: u16 bf16 writes into [128 p][128 ch] tile
    float bias_c[4];
#pragma unroll
    for (int cb = 0; cb < 4; ++cb) bias_c[cb] = bias[wc * 64 + cb * 16 + (l & 15)];

#pragma unroll
    for (int pb = 0; pb < 4; ++pb) {
#pragma unroll
        for (int cb = 0; cb < 4; ++cb) {
            int c = wc * 64 + cb * 16 + (l & 15);
#pragma unroll
            for (int q = 0; q < 4; ++q) {
                int prow = wr * 64 + pb * 16 + (l >> 4) * 4 + q;
                float v = acc[pb][cb][q] + bias_c[cb];
                int byteoff = (prow * 256 + c * 2) ^ (((prow >> 2) & 3) << 5);
                *(unsigned short*)(lbuf + byteoff) = (unsigned short)bf16_rne(v);
            }
        }
    }
    __syncthreads();

    // epilogue stage 2: 16 lanes x uint4 = full 256B row per point
#pragma unroll
    for (int j = 0; j < 8; ++j) {
        int s = j * 256 + tid;
        int prow = s >> 4, chunk = s & 15;
        int byteoff = (prow * 256 + chunk * 16) ^ (((prow >> 2) & 3) << 5);
        uint4 val = *(const uint4*)(lbuf + byteoff);
        int pos = psl[prow];
        *((uint4*)(bevf + (size_t)pos * 64) + chunk) = val;
    }
}

// ---------------- pass 5: quarter-wave uint4 streaming reduction -> float4 BCHW writeout ----------------
// Boundaries: global_start(cell c+1) = mut_cellstart[c] + cko[c>>10] (cko scanned per block).
__global__ __launch_bounds__(512) void reduce_kernel(
        const unsigned* __restrict__ bevf, const int* __restrict__ cellstart,
        const int* __restrict__ chunksum, float* __restrict__ out) {
    __shared__ unsigned tile[256 * 64];   // 64 KiB
    __shared__ int cko[512];
    int t = threadIdx.x;
    {   // exclusive scan of chunksum (first 256 entries meaningful)
        int s = (t < 256) ? chunksum[t] : 0;
        cko[t] = s;
        __syncthreads();
        for (int d = 1; d < 512; d <<= 1) {
            int x = (t >= d) ? cko[t - d] : 0;
            __syncthreads();
            cko[t] += x;
            __syncthreads();
        }
        int excl = cko[t] - s;
        __syncthreads();
        cko[t] = excl;
        __syncthreads();
    }

    int blk = blockIdx.x;
    blk = (blk & 7) * (NSEG / 8) + (blk >> 3);   // XCD-contiguous segments
    int seg = blk;

    int qw = t >> 4;          // quarter-wave 0..31
    int m  = t & 15;          // lane within quarter-wave
    int w0 = qw * 8;          // first cell (w index) of this quarter-wave
    int cell0 = seg * WWD + w0;

    int idx = cell0 + m - 1;
    int bound = 0;
    if (m <= 8) bound = (idx < 0) ? 0 : cellstart[idx] + cko[idx >> 10];
    int r0 = __shfl(bound, 0, 16);
    int r1 = __shfl(bound, 8, 16);

    float f[8];
#pragma unroll
    for (int i = 0; i < 8; ++i) f[i] = 0.f;
    int j = 0;
    int ce = __shfl(bound, 1, 16);

    for (int r = r0; r < r1; r += 4) {
        uint4 v[4];
#pragma unroll
        for (int u = 0; u < 4; ++u) {
            int rr = (r + u < r1) ? r + u : r1 - 1;
            v[u] = *(const uint4*)&bevf[(size_t)(rr + 1) * 64 + 4 * m];  // 1KB/wave stream
        }
#pragma unroll
        for (int u = 0; u < 4; ++u) {
            if (r + u >= r1) break;
            while (r + u >= ce) {                     // quarter-wave-uniform cell advance
                int w = w0 + j;
                int sb = w + (w >> 2);
                tile[w * 64 + ((4 * m + 0 + sb) & 63)] = pack2(f[0], f[1]);
                tile[w * 64 + ((4 * m + 1 + sb) & 63)] = pack2(f[2], f[3]);
                tile[w * 64 + ((4 * m + 2 + sb) & 63)] = pack2(f[4], f[5]);
                tile[w * 64 + ((4 * m + 3 + sb) & 63)] = pack2(f[6], f[7]);
#pragma unroll
                for (int i = 0; i < 8; ++i) f[i] = 0.f;
                ++j;
                ce = __shfl(bound, j + 1, 16);
            }
            f[0] += __uint_as_float(v[u].x << 16);
            f[1] += __uint_as_float(v[u].x & 0xFFFF0000u);
            f[2] += __uint_as_float(v[u].y << 16);
            f[3] += __uint_as_float(v[u].y & 0xFFFF0000u);
            f[4] += __uint_as_float(v[u].z << 16);
            f[5] += __uint_as_float(v[u].z & 0xFFFF0000u);
            f[6] += __uint_as_float(v[u].w << 16);
            f[7] += __uint_as_float(v[u].w & 0xFFFF0000u);
        }
    }
    while (j < 8) {                                   // flush tail (+empty cells)
        int w = w0 + j;
        int sb = w + (w >> 2);
        tile[w * 64 + ((4 * m + 0 + sb) & 63)] = pack2(f[0], f[1]);
        tile[w * 64 + ((4 * m + 1 + sb) & 63)] = pack2(f[2], f[3]);
        tile[w * 64 + ((4 * m + 2 + sb) & 63)] = pack2(f[4], f[5]);
        tile[w * 64 + ((4 * m + 3 + sb) & 63)] = pack2(f[6], f[7]);
#pragma unroll
        for (int i = 0; i < 8; ++i) f[i] = 0.f;
        ++j;
    }
    __syncthreads();

    int wv = t >> 6, l = t & 63;
    int b = seg >> 8, h = seg & 255;
    float* ob = out + (size_t)b * OUTC * HWD + (size_t)h * WWD;
#pragma unroll
    for (int r = 0; r < 16; ++r) {
        int c = wv + 8 * r;
        int d = c >> 1;
        bool hi = c & 1;
        unsigned v0 = tile[(4 * l + 0) * 64 + ((d + 5 * l + 0) & 63)];
        unsigned v1 = tile[(4 * l + 1) * 64 + ((d + 5 * l + 1) & 63)];
        unsigned v2 = tile[(4 * l + 2) * 64 + ((d + 5 * l + 2) & 63)];
        unsigned v3 = tile[(4 * l + 3) * 64 + ((d + 5 * l + 3) & 63)];
        float4 o;
        o.x = __uint_as_float(hi ? (v0 & 0xFFFF0000u) : (v0 << 16));
        o.y = __uint_as_float(hi ? (v1 & 0xFFFF0000u) : (v1 << 16));
        o.z = __uint_as_float(hi ? (v2 & 0xFFFF0000u) : (v2 << 16));
        o.w = __uint_as_float(hi ? (v3 & 0xFFFF0000u) : (v3 << 16));
        *(float4*)(ob + (size_t)c * HWD + 4 * l) = o;   // 1KB per wave-instr
    }
}

// ---------------- fallback (ws too small): direct scattered atomics into BCHW ----------------
__global__ __launch_bounds__(256) void naive_kernel(
        const float* __restrict__ features, const float* __restrict__ kw,
        const float* __restrict__ bias,
        const int* __restrict__ bidx, const int* __restrict__ d0,
        const int* __restrict__ d1, const int* __restrict__ zi,
        float* __restrict__ out, int n) {
    long long gid = (long long)blockIdx.x * blockDim.x + threadIdx.x;
    int pid = (int)(gid >> 7);
    int c   = (int)(gid & (OUTC - 1));
    if (pid >= n) return;
    int z = zi[pid]; z = z < 0 ? 0 : (z > NZ - 1 ? NZ - 1 : z);
    const float4* fp = (const float4*)(features + (size_t)pid * INC);
    const float* wp = kw + (size_t)z * INC * OUTC + c;
    float a0 = bias[c], a1 = 0.f, a2 = 0.f, a3 = 0.f;
#pragma unroll
    for (int i = 0; i < INC / 4; ++i) {
        float4 f = fp[i];
        a0 += f.x * wp[(size_t)(4 * i + 0) * OUTC];
        a1 += f.y * wp[(size_t)(4 * i + 1) * OUTC];
        a2 += f.z * wp[(size_t)(4 * i + 2) * OUTC];
        a3 += f.w * wp[(size_t)(4 * i + 3) * OUTC];
    }
    float acc = (a0 + a1) + (a2 + a3);
    size_t oidx = ((size_t)bidx[pid] * OUTC + c) * HWD + (size_t)d0[pid] * WWD + d1[pid];
    unsafeAtomicAdd(&out[oidx], acc);
}

extern "C" void kernel_launch(void* const* d_in, const int* in_sizes, int n_in,
                              void* d_out, int out_size, void* d_ws, size_t ws_size,
                              hipStream_t stream) {
    const float* features = (const float*)d_in[0];
    const float* kw       = (const float*)d_in[1];
    const float* bias     = (const float*)d_in[2];
    const int* batch_idx  = (const int*)d_in[3];
    const int* d0_idx     = (const int*)d_in[4];
    const int* d1_idx     = (const int*)d_in[5];
    const int* z_idx      = (const int*)d_in[6];
    float* out = (float*)d_out;
    int n = in_sizes[0] / INC;   // number of points

    size_t binsElems = (size_t)n + (size_t)NZ * PPB;
    size_t bevfBytes = (binsElems + 1) * OUTC * 2;           // ~77.5 MB
    size_t wtOff     = (bevfBytes + 255) & ~(size_t)255;     // bf16 Wt: 128 KiB
    size_t metaOff   = wtOff + (size_t)NZ * OUTC * INC * 2;
    size_t chOff     = (metaOff + 32 * 4 + 255) & ~(size_t)255;   // cellhist
    size_t csOff     = chOff + (size_t)NCELL * 4;            // cellstart (NCELL+4)
    size_t ckOff     = csOff + (size_t)(NCELL + 4) * 4;      // chunksum (256)
    size_t binsOff   = (ckOff + 256 * 4 + 255) & ~(size_t)255;
    size_t posOff    = binsOff + binsElems * 4;
    size_t need      = posOff + binsElems * 4 + 16;

    if (ws_size >= need) {
        char* ws = (char*)d_ws;
        unsigned* bevf = (unsigned*)ws;
        unsigned short* wt = (unsigned short*)(ws + wtOff);
        int* meta      = (int*)(ws + metaOff);   // counts[8], cursors[8], pstart[9]
        int* counts    = meta;
        int* cursors   = meta + 8;
        int* pstart    = meta + 16;
        int* cellhist  = (int*)(ws + chOff);
        int* cellstart = (int*)(ws + csOff);
        int* chunksum  = (int*)(ws + ckOff);
        int* bins      = (int*)(ws + binsOff);
        int* segpos    = (int*)(ws + posOff);

        int gb = (n + 255) / 256;
        wprep_kernel<<<NZ, 256, 0, stream>>>(kw, wt, meta, cellhist);
        hist_kernel<<<gb, 256, 0, stream>>>(z_idx, batch_idx, d0_idx, d1_idx,
                                            counts, cellhist, n);
        scan_local<<<256, 256, 0, stream>>>(cellhist, cellstart, chunksum,
                                            counts, pstart);
        scatter_kernel<<<gb, 256, 0, stream>>>(z_idx, batch_idx, d0_idx, d1_idx,
                                               pstart, cursors, cellstart, chunksum,
                                               bins, segpos, n);

        int nblk = (int)((binsElems + PPB - 1) / PPB) + 1;
        gemm_kernel<<<nblk, 256, 0, stream>>>(features, wt, bias, counts, pstart,
                                              bins, segpos, bevf);

        reduce_kernel<<<NSEG, 512, 0, stream>>>(bevf, cellstart, chunksum, out);
    } else {
        hipMemsetAsync(out, 0, (size_t)out_size * sizeof(float), stream);
        long long threads = (long long)n * OUTC;
        int gb = (int)((threads + 255) / 256);
        naive_kernel<<<gb, 256, 0, stream>>>(features, kw, bias, batch_idx, d0_idx,
                                             d1_idx, z_idx, out, n);
    }
}